// Round 1
// baseline (3559.426 us; speedup 1.0000x reference)
//
#include <hip/hip_runtime.h>
#include <hip/hip_bf16.h>

// Problem constants
#define BB   2
#define LI   1024
#define LC   256
#define SEQ  1280      // LC + LI
#define HDIM 1024
#define NH   16
#define HD   64
#define MLPD 4096
#define EPS  1e-6f

// ---------------------------------------------------------------------------
// RMSNorm over rows of length 1024. One block (256 threads) per row.
__launch_bounds__(256)
__global__ void rmsnorm_rows(const float* __restrict__ x,
                             const float* __restrict__ w,
                             float* __restrict__ y)
{
    const int row = blockIdx.x;
    const int t   = threadIdx.x;
    const float4* xr = (const float4*)(x + (size_t)row * HDIM);
    float4 v = xr[t];
    float ss = v.x*v.x + v.y*v.y + v.z*v.z + v.w*v.w;
    for (int o = 32; o > 0; o >>= 1) ss += __shfl_xor(ss, o);
    __shared__ float red[4];
    if ((t & 63) == 0) red[t >> 6] = ss;
    __syncthreads();
    float tot = red[0] + red[1] + red[2] + red[3];
    float inv = rsqrtf(tot * (1.0f / HDIM) + EPS);
    const float4* wr = (const float4*)w;
    float4 wv = wr[t];
    float4 o4;
    o4.x = v.x * inv * wv.x;
    o4.y = v.y * inv * wv.y;
    o4.z = v.z * inv * wv.z;
    o4.w = v.w * inv * wv.w;
    ((float4*)(y + (size_t)row * HDIM))[t] = o4;
}

// ---------------------------------------------------------------------------
// C(M,N) = epilogue( A(M,K) @ W(N,K)^T + bias )
// mode 0: C = acc + bias
// mode 1: C = residual + scale * (acc + bias)      (scale from device ptr, or 1)
// mode 2: C = silu(C_old) * (acc + bias)           (SwiGLU second pass)
// Tile 64x64, BK=16, 256 threads, 4x4 per thread. LDS stored [k][m] so
// fragment reads are ds_read_b128.
__launch_bounds__(256)
__global__ void gemm_bt(const float* __restrict__ A, const float* __restrict__ W,
                        const float* __restrict__ bias, float* __restrict__ C,
                        int M, int N, int K,
                        const float* __restrict__ residual,
                        const float* __restrict__ scale_ptr, int mode)
{
    __shared__ float As[16][64];
    __shared__ float Ws[16][64];
    const int bm = blockIdx.y * 64, bn = blockIdx.x * 64;
    const int t  = threadIdx.x;
    const int tx = t & 15, ty = t >> 4;
    const int lr = t >> 2, lc = (t & 3) * 4;

    float acc[4][4] = {};
    const float* Ab = A + (size_t)(bm + lr) * K + lc;
    const float* Wb = W + (size_t)(bn + lr) * K + lc;

    for (int k0 = 0; k0 < K; k0 += 16) {
        float4 av = *(const float4*)(Ab + k0);
        float4 wv = *(const float4*)(Wb + k0);
        __syncthreads();
        As[lc + 0][lr] = av.x; As[lc + 1][lr] = av.y;
        As[lc + 2][lr] = av.z; As[lc + 3][lr] = av.w;
        Ws[lc + 0][lr] = wv.x; Ws[lc + 1][lr] = wv.y;
        Ws[lc + 2][lr] = wv.z; Ws[lc + 3][lr] = wv.w;
        __syncthreads();
#pragma unroll
        for (int kk = 0; kk < 16; ++kk) {
            float4 a4 = *(const float4*)&As[kk][ty * 4];
            float4 b4 = *(const float4*)&Ws[kk][tx * 4];
            acc[0][0] += a4.x * b4.x; acc[0][1] += a4.x * b4.y;
            acc[0][2] += a4.x * b4.z; acc[0][3] += a4.x * b4.w;
            acc[1][0] += a4.y * b4.x; acc[1][1] += a4.y * b4.y;
            acc[1][2] += a4.y * b4.z; acc[1][3] += a4.y * b4.w;
            acc[2][0] += a4.z * b4.x; acc[2][1] += a4.z * b4.y;
            acc[2][2] += a4.z * b4.z; acc[2][3] += a4.z * b4.w;
            acc[3][0] += a4.w * b4.x; acc[3][1] += a4.w * b4.y;
            acc[3][2] += a4.w * b4.z; acc[3][3] += a4.w * b4.w;
        }
    }

    const float scale = scale_ptr ? scale_ptr[0] : 1.0f;
    float4 bb = *(const float4*)(bias + bn + tx * 4);
#pragma unroll
    for (int i = 0; i < 4; ++i) {
        const int m = bm + ty * 4 + i;
        const size_t off = (size_t)m * N + bn + tx * 4;
        float4 vo;
        vo.x = acc[i][0] + bb.x; vo.y = acc[i][1] + bb.y;
        vo.z = acc[i][2] + bb.z; vo.w = acc[i][3] + bb.w;
        if (mode == 1) {
            float4 r = *(const float4*)(residual + off);
            vo.x = r.x + scale * vo.x; vo.y = r.y + scale * vo.y;
            vo.z = r.z + scale * vo.z; vo.w = r.w + scale * vo.w;
        } else if (mode == 2) {
            float4 c = *(const float4*)(C + off);
            vo.x *= c.x / (1.0f + __expf(-c.x));
            vo.y *= c.y / (1.0f + __expf(-c.y));
            vo.z *= c.z / (1.0f + __expf(-c.z));
            vo.w *= c.w / (1.0f + __expf(-c.w));
        }
        *(float4*)(C + off) = vo;
    }
}

// ---------------------------------------------------------------------------
// Per-head RMSNorm(HD) + RoPE on q,k; copy v. Builds (B,NH,SEQ,HD) tensors
// with concat ordering: s<LC -> cond stream, else img stream.
__launch_bounds__(64)
__global__ void qkv_prep(const float* __restrict__ qkv_img,
                         const float* __restrict__ qkv_cond,
                         const float* __restrict__ img_qn, const float* __restrict__ img_kn,
                         const float* __restrict__ cond_qn, const float* __restrict__ cond_kn,
                         const float* __restrict__ icos, const float* __restrict__ isin,
                         const float* __restrict__ ccos, const float* __restrict__ csin,
                         float* __restrict__ q, float* __restrict__ k, float* __restrict__ v)
{
    const int h = blockIdx.x;   // head
    const int s = blockIdx.y;   // seq position (concat ordering)
    const int b = blockIdx.z;
    const int d = threadIdx.x;  // 0..63

    const float *src, *qw, *kw, *cs, *sn;
    int srow;
    if (s < LC) {
        src = qkv_cond; srow = b * LC + s;
        qw = cond_qn; kw = cond_kn;
        cs = ccos + (size_t)s * HD; sn = csin + (size_t)s * HD;
    } else {
        src = qkv_img; srow = b * LI + (s - LC);
        qw = img_qn; kw = img_kn;
        cs = icos + (size_t)(s - LC) * HD; sn = isin + (size_t)(s - LC) * HD;
    }
    const float* base = src + (size_t)srow * (3 * HDIM) + h * HD;
    float qv = base[d];
    float kv = base[HDIM + d];
    float vv = base[2 * HDIM + d];

    float sq = qv * qv;
    for (int o = 32; o > 0; o >>= 1) sq += __shfl_xor(sq, o);
    float qn = qv * rsqrtf(sq * (1.0f / HD) + EPS) * qw[d];
    float sk = kv * kv;
    for (int o = 32; o > 0; o >>= 1) sk += __shfl_xor(sk, o);
    float kn = kv * rsqrtf(sk * (1.0f / HD) + EPS) * kw[d];

    const float c = cs[d], s_ = sn[d];
    float qp = __shfl_xor(qn, 32);
    float kp = __shfl_xor(kn, 32);
    float qrot = (d < 32) ? -qp : qp;
    float krot = (d < 32) ? -kp : kp;

    const size_t oidx = (((size_t)b * NH + h) * SEQ + s) * HD + d;
    q[oidx] = qn * c + qrot * s_;
    k[oidx] = kn * c + krot * s_;
    v[oidx] = vv;
}

// ---------------------------------------------------------------------------
// Attention: one block (256 thr) per (b, h, query-row). Scores in LDS,
// softmax, then weighted sum of V. Writes transposed (B,S,NH*HD) layout,
// split into cond / img output buffers.
__launch_bounds__(256)
__global__ void attn(const float* __restrict__ q, const float* __restrict__ k,
                     const float* __restrict__ v,
                     float* __restrict__ o_cond, float* __restrict__ o_img)
{
    const int qi = blockIdx.x;   // 0..SEQ-1
    const int h  = blockIdx.y;
    const int b  = blockIdx.z;
    const int bh = b * NH + h;
    const int t  = threadIdx.x;

    __shared__ float qs[HD];
    __shared__ float sc[SEQ];
    __shared__ float r4[4];
    __shared__ float s4[4];
    __shared__ float ored[4][HD];

    const float* qrow = q + ((size_t)bh * SEQ + qi) * HD;
    if (t < HD) qs[t] = qrow[t];
    __syncthreads();

    const float* kb = k + (size_t)bh * SEQ * HD;
    float lmax = -1e30f;
    for (int j = t; j < SEQ; j += 256) {
        const float4* kp = (const float4*)(kb + (size_t)j * HD);
        const float4* qp = (const float4*)qs;
        float s = 0.f;
#pragma unroll
        for (int i = 0; i < 16; ++i) {
            float4 a = qp[i], c = kp[i];
            s += a.x * c.x + a.y * c.y + a.z * c.z + a.w * c.w;
        }
        s *= 0.125f;   // 1/sqrt(64)
        sc[j] = s;
        lmax = fmaxf(lmax, s);
    }
    for (int o = 32; o > 0; o >>= 1) lmax = fmaxf(lmax, __shfl_xor(lmax, o));
    if ((t & 63) == 0) r4[t >> 6] = lmax;
    __syncthreads();
    const float mx = fmaxf(fmaxf(r4[0], r4[1]), fmaxf(r4[2], r4[3]));

    float lsum = 0.f;
    for (int j = t; j < SEQ; j += 256) {
        float e = __expf(sc[j] - mx);
        sc[j] = e;
        lsum += e;
    }
    for (int o = 32; o > 0; o >>= 1) lsum += __shfl_xor(lsum, o);
    if ((t & 63) == 0) s4[t >> 6] = lsum;
    __syncthreads();
    const float inv = 1.0f / (s4[0] + s4[1] + s4[2] + s4[3]);

    const int d = t & 63, c = t >> 6;        // 4 chunks x 320 keys
    const float* vb = v + (size_t)bh * SEQ * HD;
    float acc = 0.f;
    const int j0 = c * 320, j1 = j0 + 320;
    for (int j = j0; j < j1; ++j) acc += sc[j] * vb[(size_t)j * HD + d];
    ored[c][d] = acc;
    __syncthreads();
    if (c == 0) {
        float o = (ored[0][d] + ored[1][d] + ored[2][d] + ored[3][d]) * inv;
        if (qi < LC) o_cond[((size_t)b * LC + qi) * HDIM + h * HD + d] = o;
        else         o_img [((size_t)b * LI + (qi - LC)) * HDIM + h * HD + d] = o;
    }
}

// ---------------------------------------------------------------------------
extern "C" void kernel_launch(void* const* d_in, const int* in_sizes, int n_in,
                              void* d_out, int out_size, void* d_ws, size_t ws_size,
                              hipStream_t stream)
{
    const float* image_tokens = (const float*)d_in[0];
    const float* cond_tokens  = (const float*)d_in[1];
    const float* icos  = (const float*)d_in[2];
    const float* isin  = (const float*)d_in[3];
    const float* ccos  = (const float*)d_in[4];
    const float* csin  = (const float*)d_in[5];
    const float* img_n1w  = (const float*)d_in[6];
    const float* cond_n1w = (const float*)d_in[7];
    const float* img_qkv_w  = (const float*)d_in[8];
    const float* img_qkv_b  = (const float*)d_in[9];
    const float* cond_qkv_w = (const float*)d_in[10];
    const float* cond_qkv_b = (const float*)d_in[11];
    const float* img_qn  = (const float*)d_in[12];
    const float* img_kn  = (const float*)d_in[13];
    const float* cond_qn = (const float*)d_in[14];
    const float* cond_kn = (const float*)d_in[15];
    const float* img_out_w  = (const float*)d_in[16];
    const float* img_out_b  = (const float*)d_in[17];
    const float* cond_out_w = (const float*)d_in[18];
    const float* cond_out_b = (const float*)d_in[19];
    const float* img_n2w  = (const float*)d_in[20];
    const float* cond_n2w = (const float*)d_in[21];
    const float* img_w1 = (const float*)d_in[22];
    const float* img_b1 = (const float*)d_in[23];
    const float* img_w2 = (const float*)d_in[24];
    const float* img_b2 = (const float*)d_in[25];
    const float* img_w3 = (const float*)d_in[26];
    const float* img_b3 = (const float*)d_in[27];
    const float* cond_w1 = (const float*)d_in[28];
    const float* cond_b1 = (const float*)d_in[29];
    const float* cond_w2 = (const float*)d_in[30];
    const float* cond_b2 = (const float*)d_in[31];
    const float* cond_w3 = (const float*)d_in[32];
    const float* cond_b3 = (const float*)d_in[33];
    const float* alpha = (const float*)d_in[34];
    const float* beta  = (const float*)d_in[35];

    float* out_img  = (float*)d_out;                       // (2,1024,1024)
    float* out_cond = (float*)d_out + (size_t)BB * LI * HDIM; // (2,256,1024)

    float* ws = (float*)d_ws;
    // Region P (phase 1: xn + qkv; phase 3: h). 10485760 floats.
    float* xn_img   = ws;                      // 2097152
    float* xn_cond  = ws + 2097152;            // 524288
    float* qkv_img  = ws + 2621440;            // 6291456
    float* qkv_cond = ws + 8912896;            // 1572864
    float* h_img    = ws;                      // 8388608  (reuse of P)
    float* h_cond   = ws + 8388608;            // 2097152
    float* q  = ws + 10485760;                 // 2621440
    float* k  = ws + 13107200;                 // 2621440
    float* v  = ws + 15728640;                 // 2621440
    float* o_cond = ws + 18350080;             // 524288
    float* o_img  = ws + 18874368;             // 2097152
    float* t2_cond = ws + 20971520;            // 524288
    float* t2_img  = ws + 21495808;            // 2097152
    float* n2_cond = o_cond;                   // reuse (o dead after proj)
    float* n2_img  = o_img;
    // Peak: 23592960 floats = 94.4 MB

    // 1. norm1
    rmsnorm_rows<<<BB * LI, 256, 0, stream>>>(image_tokens, img_n1w, xn_img);
    rmsnorm_rows<<<BB * LC, 256, 0, stream>>>(cond_tokens, cond_n1w, xn_cond);

    // 2. qkv projections
    gemm_bt<<<dim3(3 * HDIM / 64, BB * LI / 64), 256, 0, stream>>>(
        xn_img, img_qkv_w, img_qkv_b, qkv_img, BB * LI, 3 * HDIM, HDIM,
        nullptr, nullptr, 0);
    gemm_bt<<<dim3(3 * HDIM / 64, BB * LC / 64), 256, 0, stream>>>(
        xn_cond, cond_qkv_w, cond_qkv_b, qkv_cond, BB * LC, 3 * HDIM, HDIM,
        nullptr, nullptr, 0);

    // 3. per-head norm + rope + concat into (B,NH,SEQ,HD)
    qkv_prep<<<dim3(NH, SEQ, BB), 64, 0, stream>>>(
        qkv_img, qkv_cond, img_qn, img_kn, cond_qn, cond_kn,
        icos, isin, ccos, csin, q, k, v);

    // 4. attention
    attn<<<dim3(SEQ, NH, BB), 256, 0, stream>>>(q, k, v, o_cond, o_img);

    // 5. output projections + residual (img scaled by alpha)
    gemm_bt<<<dim3(HDIM / 64, BB * LC / 64), 256, 0, stream>>>(
        o_cond, cond_out_w, cond_out_b, t2_cond, BB * LC, HDIM, HDIM,
        cond_tokens, nullptr, 1);
    gemm_bt<<<dim3(HDIM / 64, BB * LI / 64), 256, 0, stream>>>(
        o_img, img_out_w, img_out_b, t2_img, BB * LI, HDIM, HDIM,
        image_tokens, alpha, 1);

    // 6. norm2
    rmsnorm_rows<<<BB * LC, 256, 0, stream>>>(t2_cond, cond_n2w, n2_cond);
    rmsnorm_rows<<<BB * LI, 256, 0, stream>>>(t2_img, img_n2w, n2_img);

    // 7. MLP up: h = silu(x@w1^T+b1) * (x@w2^T+b2)
    gemm_bt<<<dim3(MLPD / 64, BB * LC / 64), 256, 0, stream>>>(
        n2_cond, cond_w1, cond_b1, h_cond, BB * LC, MLPD, HDIM,
        nullptr, nullptr, 0);
    gemm_bt<<<dim3(MLPD / 64, BB * LC / 64), 256, 0, stream>>>(
        n2_cond, cond_w2, cond_b2, h_cond, BB * LC, MLPD, HDIM,
        nullptr, nullptr, 2);
    gemm_bt<<<dim3(MLPD / 64, BB * LI / 64), 256, 0, stream>>>(
        n2_img, img_w1, img_b1, h_img, BB * LI, MLPD, HDIM,
        nullptr, nullptr, 0);
    gemm_bt<<<dim3(MLPD / 64, BB * LI / 64), 256, 0, stream>>>(
        n2_img, img_w2, img_b2, h_img, BB * LI, MLPD, HDIM,
        nullptr, nullptr, 2);

    // 8. MLP down + residual (img scaled by beta) -> d_out
    gemm_bt<<<dim3(HDIM / 64, BB * LC / 64), 256, 0, stream>>>(
        h_cond, cond_w3, cond_b3, out_cond, BB * LC, HDIM, MLPD,
        t2_cond, nullptr, 1);
    gemm_bt<<<dim3(HDIM / 64, BB * LI / 64), 256, 0, stream>>>(
        h_img, img_w3, img_b3, out_img, BB * LI, HDIM, MLPD,
        t2_img, beta, 1);
}

// Round 2
// 747.962 us; speedup vs baseline: 4.7588x; 4.7588x over previous
//
#include <hip/hip_runtime.h>
#include <hip/hip_bf16.h>

// Problem constants
#define BB   2
#define LI   1024
#define LC   256
#define SEQ  1280      // LC + LI
#define HDIM 1024
#define NH   16
#define HD   64
#define MLPD 4096
#define EPS  1e-6f

typedef __bf16 bf16x8 __attribute__((ext_vector_type(8)));
typedef float f32x4 __attribute__((ext_vector_type(4)));
typedef unsigned short us4 __attribute__((ext_vector_type(4)));

static __device__ __forceinline__ unsigned short f2bf(float f) {
    unsigned int u = __builtin_bit_cast(unsigned int, f);
    u += 0x7fffu + ((u >> 16) & 1u);
    return (unsigned short)(u >> 16);
}

// async global->LDS, 16B per lane. LDS dst must be wave-uniform; global src per-lane.
static __device__ __forceinline__ void gload_lds16(const void* g, void* l) {
    __builtin_amdgcn_global_load_lds((__attribute__((address_space(1))) void*)(g),
                                     (__attribute__((address_space(3))) void*)(l),
                                     16, 0, 0);
}

// ---------------------------------------------------------------------------
// f32 -> bf16 elementwise convert (vectorized, grid-stride)
__global__ __launch_bounds__(256)
void cvt_f32_bf16(const float* __restrict__ x, unsigned short* __restrict__ y, int n4)
{
    int i = blockIdx.x * 256 + threadIdx.x;
    const int stride = gridDim.x * 256;
    for (; i < n4; i += stride) {
        float4 v = ((const float4*)x)[i];
        us4 o = { f2bf(v.x), f2bf(v.y), f2bf(v.z), f2bf(v.w) };
        ((us4*)y)[i] = o;
    }
}

// ---------------------------------------------------------------------------
// RMSNorm over rows of length 1024. One block (256 threads) per row.
template<typename OUT>
__global__ __launch_bounds__(256)
void rmsnorm_rows(const float* __restrict__ x, const float* __restrict__ w,
                  OUT* __restrict__ y)
{
    const int row = blockIdx.x;
    const int t   = threadIdx.x;
    const float4* xr = (const float4*)(x + (size_t)row * HDIM);
    float4 v = xr[t];
    float ss = v.x*v.x + v.y*v.y + v.z*v.z + v.w*v.w;
    for (int o = 32; o > 0; o >>= 1) ss += __shfl_xor(ss, o);
    __shared__ float red[4];
    if ((t & 63) == 0) red[t >> 6] = ss;
    __syncthreads();
    float tot = red[0] + red[1] + red[2] + red[3];
    float inv = rsqrtf(tot * (1.0f / HDIM) + EPS);
    float4 wv = ((const float4*)w)[t];
    float o0 = v.x * inv * wv.x, o1 = v.y * inv * wv.y;
    float o2 = v.z * inv * wv.z, o3 = v.w * inv * wv.w;
    if constexpr (sizeof(OUT) == 2) {
        us4 pk = { f2bf(o0), f2bf(o1), f2bf(o2), f2bf(o3) };
        *(us4*)&y[(size_t)row * HDIM + t * 4] = pk;
    } else {
        float4 o4 = { o0, o1, o2, o3 };
        *(float4*)&y[(size_t)row * HDIM + t * 4] = o4;
    }
}

// ---------------------------------------------------------------------------
// bf16 MFMA GEMM: C(M,N) = epilogue( A(M,K) @ W(N,K)^T + bias ), f32 accum.
// m97 structure: 128x128 tile, BK=32, 4 waves (2x2), 4x4 16x16 frags/wave,
// global_load_lds width-16 staging into linear LDS [128][32] bf16.
// MODE 0: C = acc + bias                      (OUT float or bf16)
// MODE 1: C = residual + scale*(acc + bias)   (scale from device ptr or 1)
// MODE 2: C = silu(gate) * (acc + bias)       (gate = f32 h1 buffer)
template<int MODE, typename OUT>
__global__ __launch_bounds__(256)
void gemm_bf16(const unsigned short* __restrict__ A,
               const unsigned short* __restrict__ W,
               const float* __restrict__ bias,
               OUT* __restrict__ C,
               int M, int N, int K,
               const float* __restrict__ residual,
               const float* __restrict__ scale_ptr,
               const float* __restrict__ gate)
{
    __shared__ __align__(16) unsigned short As[128][32];
    __shared__ __align__(16) unsigned short Ws[128][32];

    const int t    = threadIdx.x;
    const int lane = t & 63;
    const int wid  = t >> 6;
    const int wm   = wid >> 1, wn = wid & 1;
    const int bm   = blockIdx.y * 128, bn = blockIdx.x * 128;

    // staging: wave wid covers rows [wid*32, wid*32+32) in 2 instrs (j=0: +0, j=1: +16)
    const int srow = (wid << 5) + (lane >> 2);
    const int scol = (lane & 3) << 3;
    const unsigned short* Ag0 = A + (size_t)(bm + srow)      * K + scol;
    const unsigned short* Ag1 = A + (size_t)(bm + srow + 16) * K + scol;
    const unsigned short* Wg0 = W + (size_t)(bn + srow)      * K + scol;
    const unsigned short* Wg1 = W + (size_t)(bn + srow + 16) * K + scol;
    unsigned short* lA0 = &As[(wid << 5)     ][0];   // wave-uniform
    unsigned short* lA1 = &As[(wid << 5) + 16][0];
    unsigned short* lW0 = &Ws[(wid << 5)     ][0];
    unsigned short* lW1 = &Ws[(wid << 5) + 16][0];

    const int fr = lane & 15;      // frag row (A) / col (B)
    const int kg = lane >> 4;      // k-group
    const int ko = kg << 3;        // k element offset

    f32x4 acc[4][4] = {};

    for (int k0 = 0; k0 < K; k0 += 32) {
        __syncthreads();
        gload_lds16(Ag0 + k0, lA0);
        gload_lds16(Ag1 + k0, lA1);
        gload_lds16(Wg0 + k0, lW0);
        gload_lds16(Wg1 + k0, lW1);
        __syncthreads();
        bf16x8 aF[4], bF[4];
#pragma unroll
        for (int m = 0; m < 4; ++m)
            aF[m] = *(const bf16x8*)&As[wm * 64 + m * 16 + fr][ko];
#pragma unroll
        for (int n = 0; n < 4; ++n)
            bF[n] = *(const bf16x8*)&Ws[wn * 64 + n * 16 + fr][ko];
#pragma unroll
        for (int m = 0; m < 4; ++m)
#pragma unroll
            for (int n = 0; n < 4; ++n)
                acc[m][n] = __builtin_amdgcn_mfma_f32_16x16x32_bf16(
                    aF[m], bF[n], acc[m][n], 0, 0, 0);
    }

    const float scale = scale_ptr ? scale_ptr[0] : 1.0f;
#pragma unroll
    for (int n = 0; n < 4; ++n) {
        const int gc = bn + wn * 64 + n * 16 + fr;
        const float bv = bias[gc];
#pragma unroll
        for (int m = 0; m < 4; ++m) {
            const int gr0 = bm + wm * 64 + m * 16 + (kg << 2);
#pragma unroll
            for (int j = 0; j < 4; ++j) {
                const size_t off = (size_t)(gr0 + j) * N + gc;
                float vv = acc[m][n][j] + bv;
                if (MODE == 1) {
                    vv = residual[off] + scale * vv;
                } else if (MODE == 2) {
                    float g = gate[off];
                    vv = (g / (1.0f + __expf(-g))) * vv;
                }
                if constexpr (sizeof(OUT) == 2) C[off] = (OUT)f2bf(vv);
                else                            C[off] = vv;
            }
        }
    }
}

// ---------------------------------------------------------------------------
// Per-head RMSNorm(HD) + RoPE on q,k; copy v. (f32 in/out, as validated R1)
__launch_bounds__(64)
__global__ void qkv_prep(const float* __restrict__ qkv_img,
                         const float* __restrict__ qkv_cond,
                         const float* __restrict__ img_qn, const float* __restrict__ img_kn,
                         const float* __restrict__ cond_qn, const float* __restrict__ cond_kn,
                         const float* __restrict__ icos, const float* __restrict__ isin,
                         const float* __restrict__ ccos, const float* __restrict__ csin,
                         float* __restrict__ q, float* __restrict__ k, float* __restrict__ v)
{
    const int h = blockIdx.x;
    const int s = blockIdx.y;
    const int b = blockIdx.z;
    const int d = threadIdx.x;

    const float *src, *qw, *kw, *cs, *sn;
    int srow;
    if (s < LC) {
        src = qkv_cond; srow = b * LC + s;
        qw = cond_qn; kw = cond_kn;
        cs = ccos + (size_t)s * HD; sn = csin + (size_t)s * HD;
    } else {
        src = qkv_img; srow = b * LI + (s - LC);
        qw = img_qn; kw = img_kn;
        cs = icos + (size_t)(s - LC) * HD; sn = isin + (size_t)(s - LC) * HD;
    }
    const float* base = src + (size_t)srow * (3 * HDIM) + h * HD;
    float qv = base[d];
    float kv = base[HDIM + d];
    float vv = base[2 * HDIM + d];

    float sq = qv * qv;
    for (int o = 32; o > 0; o >>= 1) sq += __shfl_xor(sq, o);
    float qn = qv * rsqrtf(sq * (1.0f / HD) + EPS) * qw[d];
    float sk = kv * kv;
    for (int o = 32; o > 0; o >>= 1) sk += __shfl_xor(sk, o);
    float kn = kv * rsqrtf(sk * (1.0f / HD) + EPS) * kw[d];

    const float c = cs[d], s_ = sn[d];
    float qp = __shfl_xor(qn, 32);
    float kp = __shfl_xor(kn, 32);
    float qrot = (d < 32) ? -qp : qp;
    float krot = (d < 32) ? -kp : kp;

    const size_t oidx = (((size_t)b * NH + h) * SEQ + s) * HD + d;
    q[oidx] = qn * c + qrot * s_;
    k[oidx] = kn * c + krot * s_;
    v[oidx] = vv;
}

// ---------------------------------------------------------------------------
// Flash attention, f32. Block = (64-query tile, h, b), 256 threads (16x16).
// Per kv-tile (64): stage K^T,V in LDS; S via 4x4 micro-GEMM; online softmax
// on wave 0; rescale+PV via 4x4 micro-GEMM. Output bf16 (out-proj input).
__global__ __launch_bounds__(256)
void attn_flash(const float* __restrict__ q, const float* __restrict__ k,
                const float* __restrict__ v,
                unsigned short* __restrict__ o_cond, unsigned short* __restrict__ o_img)
{
    const int q0 = blockIdx.x * 64;
    const int h  = blockIdx.y;
    const int b  = blockIdx.z;
    const int bh = b * NH + h;
    const int t  = threadIdx.x;
    const int tx = t & 15, ty = t >> 4;

    __shared__ __align__(16) float QsT[64][68];   // [d][r], pre-scaled by 1/8
    __shared__ __align__(16) float KsT[64][68];   // [d][c]
    __shared__ __align__(16) float Vs [64][68];   // [kk][d]
    __shared__ __align__(16) float PsT[64][68];   // [c][r]
    __shared__ float alpha_l[64];
    __shared__ float linv_l[64];

    const float* qb = q + (size_t)bh * SEQ * HD;
    const float* kb = k + (size_t)bh * SEQ * HD;
    const float* vb = v + (size_t)bh * SEQ * HD;

    // stage Q transposed, folding in the 1/sqrt(HD) scale
#pragma unroll
    for (int p = 0; p < 4; ++p) {
        int l = p * 256 + t;
        int r = l >> 4, d4 = (l & 15) << 2;
        float4 val = *(const float4*)&qb[(size_t)(q0 + r) * HD + d4];
        QsT[d4 + 0][r] = val.x * 0.125f; QsT[d4 + 1][r] = val.y * 0.125f;
        QsT[d4 + 2][r] = val.z * 0.125f; QsT[d4 + 3][r] = val.w * 0.125f;
    }

    float O[4][4] = {};
    float m_r = -1e30f, l_r = 0.0f;   // live on wave 0 only

    for (int tile = 0; tile < SEQ / 64; ++tile) {
        __syncthreads();   // prev PV done before overwriting K/V
#pragma unroll
        for (int p = 0; p < 4; ++p) {
            int l = p * 256 + t;
            int r = l >> 4, d4 = (l & 15) << 2;
            float4 kv = *(const float4*)&kb[(size_t)(tile * 64 + r) * HD + d4];
            KsT[d4 + 0][r] = kv.x; KsT[d4 + 1][r] = kv.y;
            KsT[d4 + 2][r] = kv.z; KsT[d4 + 3][r] = kv.w;
            float4 vv = *(const float4*)&vb[(size_t)(tile * 64 + r) * HD + d4];
            *(float4*)&Vs[r][d4] = vv;
        }
        __syncthreads();

        float s[4][4] = {};
#pragma unroll 8
        for (int kk = 0; kk < 64; ++kk) {
            float4 a4 = *(const float4*)&QsT[kk][ty * 4];
            float4 b4 = *(const float4*)&KsT[kk][tx * 4];
            s[0][0] += a4.x*b4.x; s[0][1] += a4.x*b4.y; s[0][2] += a4.x*b4.z; s[0][3] += a4.x*b4.w;
            s[1][0] += a4.y*b4.x; s[1][1] += a4.y*b4.y; s[1][2] += a4.y*b4.z; s[1][3] += a4.y*b4.w;
            s[2][0] += a4.z*b4.x; s[2][1] += a4.z*b4.y; s[2][2] += a4.z*b4.z; s[2][3] += a4.z*b4.w;
            s[3][0] += a4.w*b4.x; s[3][1] += a4.w*b4.y; s[3][2] += a4.w*b4.z; s[3][3] += a4.w*b4.w;
        }
#pragma unroll
        for (int j = 0; j < 4; ++j) {
            float4 col = { s[0][j], s[1][j], s[2][j], s[3][j] };
            *(float4*)&PsT[tx * 4 + j][ty * 4] = col;
        }
        __syncthreads();

        if (t < 64) {   // wave 0: per-row online softmax
            float tm = -1e30f;
            for (int c = 0; c < 64; ++c) tm = fmaxf(tm, PsT[c][t]);
            float mn = fmaxf(m_r, tm);
            float al = __expf(m_r - mn);
            float ls = 0.f;
            for (int c = 0; c < 64; ++c) {
                float p = __expf(PsT[c][t] - mn);
                PsT[c][t] = p;
                ls += p;
            }
            l_r = al * l_r + ls;
            m_r = mn;
            alpha_l[t] = al;
        }
        __syncthreads();

        float fa[4];
#pragma unroll
        for (int i = 0; i < 4; ++i) fa[i] = alpha_l[ty * 4 + i];
#pragma unroll
        for (int i = 0; i < 4; ++i)
#pragma unroll
            for (int j = 0; j < 4; ++j) O[i][j] *= fa[i];
#pragma unroll 8
        for (int kk = 0; kk < 64; ++kk) {
            float4 p4 = *(const float4*)&PsT[kk][ty * 4];
            float4 v4 = *(const float4*)&Vs[kk][tx * 4];
            O[0][0] += p4.x*v4.x; O[0][1] += p4.x*v4.y; O[0][2] += p4.x*v4.z; O[0][3] += p4.x*v4.w;
            O[1][0] += p4.y*v4.x; O[1][1] += p4.y*v4.y; O[1][2] += p4.y*v4.z; O[1][3] += p4.y*v4.w;
            O[2][0] += p4.z*v4.x; O[2][1] += p4.z*v4.y; O[2][2] += p4.z*v4.z; O[2][3] += p4.z*v4.w;
            O[3][0] += p4.w*v4.x; O[3][1] += p4.w*v4.y; O[3][2] += p4.w*v4.z; O[3][3] += p4.w*v4.w;
        }
    }

    if (t < 64) linv_l[t] = 1.0f / l_r;
    __syncthreads();

#pragma unroll
    for (int i = 0; i < 4; ++i) {
        const int qi = q0 + ty * 4 + i;
        const float inv = linv_l[ty * 4 + i];
        us4 pk = { f2bf(O[i][0] * inv), f2bf(O[i][1] * inv),
                   f2bf(O[i][2] * inv), f2bf(O[i][3] * inv) };
        if (qi < LC) {
            *(us4*)&o_cond[((size_t)b * LC + qi) * HDIM + h * HD + tx * 4] = pk;
        } else {
            *(us4*)&o_img[((size_t)b * LI + (qi - LC)) * HDIM + h * HD + tx * 4] = pk;
        }
    }
}

// ---------------------------------------------------------------------------
extern "C" void kernel_launch(void* const* d_in, const int* in_sizes, int n_in,
                              void* d_out, int out_size, void* d_ws, size_t ws_size,
                              hipStream_t stream)
{
    const float* image_tokens = (const float*)d_in[0];
    const float* cond_tokens  = (const float*)d_in[1];
    const float* icos  = (const float*)d_in[2];
    const float* isin  = (const float*)d_in[3];
    const float* ccos  = (const float*)d_in[4];
    const float* csin  = (const float*)d_in[5];
    const float* img_n1w  = (const float*)d_in[6];
    const float* cond_n1w = (const float*)d_in[7];
    const float* img_qkv_w  = (const float*)d_in[8];
    const float* img_qkv_b  = (const float*)d_in[9];
    const float* cond_qkv_w = (const float*)d_in[10];
    const float* cond_qkv_b = (const float*)d_in[11];
    const float* img_qn  = (const float*)d_in[12];
    const float* img_kn  = (const float*)d_in[13];
    const float* cond_qn = (const float*)d_in[14];
    const float* cond_kn = (const float*)d_in[15];
    const float* img_out_w  = (const float*)d_in[16];
    const float* img_out_b  = (const float*)d_in[17];
    const float* cond_out_w = (const float*)d_in[18];
    const float* cond_out_b = (const float*)d_in[19];
    const float* img_n2w  = (const float*)d_in[20];
    const float* cond_n2w = (const float*)d_in[21];
    const float* img_w1 = (const float*)d_in[22];
    const float* img_b1 = (const float*)d_in[23];
    const float* img_w2 = (const float*)d_in[24];
    const float* img_b2 = (const float*)d_in[25];
    const float* img_w3 = (const float*)d_in[26];
    const float* img_b3 = (const float*)d_in[27];
    const float* cond_w1 = (const float*)d_in[28];
    const float* cond_b1 = (const float*)d_in[29];
    const float* cond_w2 = (const float*)d_in[30];
    const float* cond_b2 = (const float*)d_in[31];
    const float* cond_w3 = (const float*)d_in[32];
    const float* cond_b3 = (const float*)d_in[33];
    const float* alpha = (const float*)d_in[34];
    const float* beta  = (const float*)d_in[35];

    float* out_img  = (float*)d_out;
    float* out_cond = (float*)d_out + (size_t)BB * LI * HDIM;

    // Arena (f32 units). Peak 23,330,816 u = 93.3 MB (<= 94.4 MB proven R1).
    float* ws = (float*)d_ws;
    unsigned short* wslot   = (unsigned short*)(ws);             // 8.39 MB, serial reuse
    unsigned short* xn_img  = (unsigned short*)(ws + 2097152);   // 2048x1024 bf16
    unsigned short* xn_cond = (unsigned short*)(ws + 3145728);   //  512x1024 bf16
    float* qkv_img  = ws + 3407872;                              // 2048x3072 f32
    float* qkv_cond = ws + 9699328;                              //  512x3072 f32
    // qkv region reused after qkv_prep:
    unsigned short* o_cond = (unsigned short*)(ws + 3407872);    //  512x1024 bf16
    unsigned short* o_img  = o_cond + 512 * 1024;                // 2048x1024 bf16
    float* t2_cond = ws + 4718592;                               //  512x1024 f32
    float* t2_img  = ws + 4718592 + 524288;                      // 2048x1024 f32
    unsigned short* n2_cond = (unsigned short*)(ws + 7340032);
    unsigned short* n2_img  = n2_cond + 512 * 1024;
    float* h1 = ws + 8650752;                                    // up to 2048x4096 f32 (over q/k/v)
    float* qf = ws + 11272192;                                   // (B,NH,SEQ,HD) f32
    float* kf = ws + 13893632;
    float* vf = ws + 16515072;
    unsigned short* hbf = (unsigned short*)(ws + 19136512);      // up to 2048x4096 bf16

    auto cvt = [&](const float* src, unsigned short* dst, int n) {
        int n4 = n >> 2;
        int blocks = (n4 + 255) / 256; if (blocks > 2048) blocks = 2048;
        cvt_f32_bf16<<<blocks, 256, 0, stream>>>(src, dst, n4);
    };

    // 1. norm1 -> bf16
    rmsnorm_rows<unsigned short><<<BB * LI, 256, 0, stream>>>(image_tokens, img_n1w, xn_img);
    rmsnorm_rows<unsigned short><<<BB * LC, 256, 0, stream>>>(cond_tokens, cond_n1w, xn_cond);

    // 2. qkv projections (bf16 MFMA, f32 out)
    cvt(img_qkv_w, wslot, 3 * HDIM * HDIM);
    gemm_bf16<0, float><<<dim3(3 * HDIM / 128, BB * LI / 128), 256, 0, stream>>>(
        xn_img, wslot, img_qkv_b, qkv_img, BB * LI, 3 * HDIM, HDIM, nullptr, nullptr, nullptr);
    cvt(cond_qkv_w, wslot, 3 * HDIM * HDIM);
    gemm_bf16<0, float><<<dim3(3 * HDIM / 128, BB * LC / 128), 256, 0, stream>>>(
        xn_cond, wslot, cond_qkv_b, qkv_cond, BB * LC, 3 * HDIM, HDIM, nullptr, nullptr, nullptr);

    // 3. per-head norm + rope + concat
    qkv_prep<<<dim3(NH, SEQ, BB), 64, 0, stream>>>(
        qkv_img, qkv_cond, img_qn, img_kn, cond_qn, cond_kn,
        icos, isin, ccos, csin, qf, kf, vf);

    // 4. flash attention -> bf16 o
    attn_flash<<<dim3(SEQ / 64, NH, BB), 256, 0, stream>>>(qf, kf, vf, o_cond, o_img);

    // 5. output projections + residual
    cvt(cond_out_w, wslot, HDIM * HDIM);
    gemm_bf16<1, float><<<dim3(HDIM / 128, BB * LC / 128), 256, 0, stream>>>(
        o_cond, wslot, cond_out_b, t2_cond, BB * LC, HDIM, HDIM, cond_tokens, nullptr, nullptr);
    cvt(img_out_w, wslot, HDIM * HDIM);
    gemm_bf16<1, float><<<dim3(HDIM / 128, BB * LI / 128), 256, 0, stream>>>(
        o_img, wslot, img_out_b, t2_img, BB * LI, HDIM, HDIM, image_tokens, alpha, nullptr);

    // 6. norm2 -> bf16
    rmsnorm_rows<unsigned short><<<BB * LC, 256, 0, stream>>>(t2_cond, cond_n2w, n2_cond);
    rmsnorm_rows<unsigned short><<<BB * LI, 256, 0, stream>>>(t2_img, img_n2w, n2_img);

    // 7. cond MLP (h1 f32 -> swiglu -> h bf16 -> down+residual)
    cvt(cond_w1, wslot, MLPD * HDIM);
    gemm_bf16<0, float><<<dim3(MLPD / 128, BB * LC / 128), 256, 0, stream>>>(
        n2_cond, wslot, cond_b1, h1, BB * LC, MLPD, HDIM, nullptr, nullptr, nullptr);
    cvt(cond_w2, wslot, MLPD * HDIM);
    gemm_bf16<2, unsigned short><<<dim3(MLPD / 128, BB * LC / 128), 256, 0, stream>>>(
        n2_cond, wslot, cond_b2, hbf, BB * LC, MLPD, HDIM, nullptr, nullptr, h1);
    cvt(cond_w3, wslot, HDIM * MLPD);
    gemm_bf16<1, float><<<dim3(HDIM / 128, BB * LC / 128), 256, 0, stream>>>(
        hbf, wslot, cond_b3, out_cond, BB * LC, HDIM, MLPD, t2_cond, nullptr, nullptr);

    // 8. img MLP (beta-scaled)
    cvt(img_w1, wslot, MLPD * HDIM);
    gemm_bf16<0, float><<<dim3(MLPD / 128, BB * LI / 128), 256, 0, stream>>>(
        n2_img, wslot, img_b1, h1, BB * LI, MLPD, HDIM, nullptr, nullptr, nullptr);
    cvt(img_w2, wslot, MLPD * HDIM);
    gemm_bf16<2, unsigned short><<<dim3(MLPD / 128, BB * LI / 128), 256, 0, stream>>>(
        n2_img, wslot, img_b2, hbf, BB * LI, MLPD, HDIM, nullptr, nullptr, h1);
    cvt(img_w3, wslot, HDIM * MLPD);
    gemm_bf16<1, float><<<dim3(HDIM / 128, BB * LI / 128), 256, 0, stream>>>(
        hbf, wslot, img_b3, out_img, BB * LI, HDIM, MLPD, t2_img, beta, nullptr);
}

// Round 3
// 541.137 us; speedup vs baseline: 6.5777x; 1.3822x over previous
//
#include <hip/hip_runtime.h>
#include <hip/hip_bf16.h>

// Problem constants
#define BB   2
#define LI   1024
#define LC   256
#define SEQ  1280      // LC + LI
#define HDIM 1024
#define NH   16
#define HD   64
#define MLPD 4096
#define EPS  1e-6f

typedef __bf16 bf16x8 __attribute__((ext_vector_type(8)));
typedef float f32x4 __attribute__((ext_vector_type(4)));
typedef unsigned short us4 __attribute__((ext_vector_type(4)));
typedef unsigned short us8 __attribute__((ext_vector_type(8)));

static __device__ __forceinline__ unsigned short f2bf(float f) {
    unsigned int u = __builtin_bit_cast(unsigned int, f);
    u += 0x7fffu + ((u >> 16) & 1u);
    return (unsigned short)(u >> 16);
}

// async global->LDS, 16B per lane. LDS dst = wave-uniform base + lane*16.
static __device__ __forceinline__ void gload_lds16(const void* g, void* l) {
    __builtin_amdgcn_global_load_lds((__attribute__((address_space(1))) void*)(g),
                                     (__attribute__((address_space(3))) void*)(l),
                                     16, 0, 0);
}

// ---------------------------------------------------------------------------
// f32 -> bf16 elementwise convert (vectorized, grid-stride)
__global__ __launch_bounds__(256)
void cvt_f32_bf16(const float* __restrict__ x, unsigned short* __restrict__ y, int n4)
{
    int i = blockIdx.x * 256 + threadIdx.x;
    const int stride = gridDim.x * 256;
    for (; i < n4; i += stride) {
        float4 v = ((const float4*)x)[i];
        us4 o = { f2bf(v.x), f2bf(v.y), f2bf(v.z), f2bf(v.w) };
        ((us4*)y)[i] = o;
    }
}

// ---------------------------------------------------------------------------
// RMSNorm over rows of length 1024. One block (256 threads) per row.
template<typename OUT>
__global__ __launch_bounds__(256)
void rmsnorm_rows(const float* __restrict__ x, const float* __restrict__ w,
                  OUT* __restrict__ y)
{
    const int row = blockIdx.x;
    const int t   = threadIdx.x;
    const float4* xr = (const float4*)(x + (size_t)row * HDIM);
    float4 v = xr[t];
    float ss = v.x*v.x + v.y*v.y + v.z*v.z + v.w*v.w;
    for (int o = 32; o > 0; o >>= 1) ss += __shfl_xor(ss, o);
    __shared__ float red[4];
    if ((t & 63) == 0) red[t >> 6] = ss;
    __syncthreads();
    float tot = red[0] + red[1] + red[2] + red[3];
    float inv = rsqrtf(tot * (1.0f / HDIM) + EPS);
    float4 wv = ((const float4*)w)[t];
    float o0 = v.x * inv * wv.x, o1 = v.y * inv * wv.y;
    float o2 = v.z * inv * wv.z, o3 = v.w * inv * wv.w;
    if constexpr (sizeof(OUT) == 2) {
        us4 pk = { f2bf(o0), f2bf(o1), f2bf(o2), f2bf(o3) };
        *(us4*)&y[(size_t)row * HDIM + t * 4] = pk;
    } else {
        float4 o4 = { o0, o1, o2, o3 };
        *(float4*)&y[(size_t)row * HDIM + t * 4] = o4;
    }
}

// ---------------------------------------------------------------------------
// bf16 MFMA GEMM (m97 structure), as validated in R2.
template<int MODE, typename OUT>
__global__ __launch_bounds__(256)
void gemm_bf16(const unsigned short* __restrict__ A,
               const unsigned short* __restrict__ W,
               const float* __restrict__ bias,
               OUT* __restrict__ C,
               int M, int N, int K,
               const float* __restrict__ residual,
               const float* __restrict__ scale_ptr,
               const float* __restrict__ gate)
{
    __shared__ __align__(16) unsigned short As[128][32];
    __shared__ __align__(16) unsigned short Ws[128][32];

    const int t    = threadIdx.x;
    const int lane = t & 63;
    const int wid  = t >> 6;
    const int wm   = wid >> 1, wn = wid & 1;
    const int bm   = blockIdx.y * 128, bn = blockIdx.x * 128;

    const int srow = (wid << 5) + (lane >> 2);
    const int scol = (lane & 3) << 3;
    const unsigned short* Ag0 = A + (size_t)(bm + srow)      * K + scol;
    const unsigned short* Ag1 = A + (size_t)(bm + srow + 16) * K + scol;
    const unsigned short* Wg0 = W + (size_t)(bn + srow)      * K + scol;
    const unsigned short* Wg1 = W + (size_t)(bn + srow + 16) * K + scol;
    unsigned short* lA0 = &As[(wid << 5)     ][0];
    unsigned short* lA1 = &As[(wid << 5) + 16][0];
    unsigned short* lW0 = &Ws[(wid << 5)     ][0];
    unsigned short* lW1 = &Ws[(wid << 5) + 16][0];

    const int fr = lane & 15;
    const int kg = lane >> 4;
    const int ko = kg << 3;

    f32x4 acc[4][4] = {};

    for (int k0 = 0; k0 < K; k0 += 32) {
        __syncthreads();
        gload_lds16(Ag0 + k0, lA0);
        gload_lds16(Ag1 + k0, lA1);
        gload_lds16(Wg0 + k0, lW0);
        gload_lds16(Wg1 + k0, lW1);
        __syncthreads();
        bf16x8 aF[4], bF[4];
#pragma unroll
        for (int m = 0; m < 4; ++m)
            aF[m] = *(const bf16x8*)&As[wm * 64 + m * 16 + fr][ko];
#pragma unroll
        for (int n = 0; n < 4; ++n)
            bF[n] = *(const bf16x8*)&Ws[wn * 64 + n * 16 + fr][ko];
#pragma unroll
        for (int m = 0; m < 4; ++m)
#pragma unroll
            for (int n = 0; n < 4; ++n)
                acc[m][n] = __builtin_amdgcn_mfma_f32_16x16x32_bf16(
                    aF[m], bF[n], acc[m][n], 0, 0, 0);
    }

    const float scale = scale_ptr ? scale_ptr[0] : 1.0f;
#pragma unroll
    for (int n = 0; n < 4; ++n) {
        const int gc = bn + wn * 64 + n * 16 + fr;
        const float bv = bias[gc];
#pragma unroll
        for (int m = 0; m < 4; ++m) {
            const int gr0 = bm + wm * 64 + m * 16 + (kg << 2);
#pragma unroll
            for (int j = 0; j < 4; ++j) {
                const size_t off = (size_t)(gr0 + j) * N + gc;
                float vv = acc[m][n][j] + bv;
                if (MODE == 1) {
                    vv = residual[off] + scale * vv;
                } else if (MODE == 2) {
                    float g = gate[off];
                    vv = (g / (1.0f + __expf(-g))) * vv;
                }
                if constexpr (sizeof(OUT) == 2) C[off] = (OUT)f2bf(vv);
                else                            C[off] = vv;
            }
        }
    }
}

// ---------------------------------------------------------------------------
// Per-head RMSNorm(HD) + RoPE on q,k; copy v. Emits bf16; q pre-scaled 1/8.
__launch_bounds__(64)
__global__ void qkv_prep(const float* __restrict__ qkv_img,
                         const float* __restrict__ qkv_cond,
                         const float* __restrict__ img_qn, const float* __restrict__ img_kn,
                         const float* __restrict__ cond_qn, const float* __restrict__ cond_kn,
                         const float* __restrict__ icos, const float* __restrict__ isin,
                         const float* __restrict__ ccos, const float* __restrict__ csin,
                         unsigned short* __restrict__ q, unsigned short* __restrict__ k,
                         unsigned short* __restrict__ v)
{
    const int h = blockIdx.x;
    const int s = blockIdx.y;
    const int b = blockIdx.z;
    const int d = threadIdx.x;

    const float *src, *qw, *kw, *cs, *sn;
    int srow;
    if (s < LC) {
        src = qkv_cond; srow = b * LC + s;
        qw = cond_qn; kw = cond_kn;
        cs = ccos + (size_t)s * HD; sn = csin + (size_t)s * HD;
    } else {
        src = qkv_img; srow = b * LI + (s - LC);
        qw = img_qn; kw = img_kn;
        cs = icos + (size_t)(s - LC) * HD; sn = isin + (size_t)(s - LC) * HD;
    }
    const float* base = src + (size_t)srow * (3 * HDIM) + h * HD;
    float qv = base[d];
    float kv = base[HDIM + d];
    float vv = base[2 * HDIM + d];

    float sq = qv * qv;
    for (int o = 32; o > 0; o >>= 1) sq += __shfl_xor(sq, o);
    float qn = qv * rsqrtf(sq * (1.0f / HD) + EPS) * qw[d];
    float sk = kv * kv;
    for (int o = 32; o > 0; o >>= 1) sk += __shfl_xor(sk, o);
    float kn = kv * rsqrtf(sk * (1.0f / HD) + EPS) * kw[d];

    const float c = cs[d], s_ = sn[d];
    float qp = __shfl_xor(qn, 32);
    float kp = __shfl_xor(kn, 32);
    float qrot = (d < 32) ? -qp : qp;
    float krot = (d < 32) ? -kp : kp;

    const size_t oidx = (((size_t)b * NH + h) * SEQ + s) * HD + d;
    q[oidx] = f2bf((qn * c + qrot * s_) * 0.125f);   // fold 1/sqrt(HD)
    k[oidx] = f2bf(kn * c + krot * s_);
    v[oidx] = f2bf(vv);
}

// ---------------------------------------------------------------------------
// 64x64 bf16 tile transpose: v [bh][s][d] -> vt [bh][d][s]
__global__ __launch_bounds__(256)
void transpose_v(const unsigned short* __restrict__ vb, unsigned short* __restrict__ vt)
{
    const int bh = blockIdx.y;
    const int s0 = blockIdx.x * 64;
    const int t  = threadIdx.x;
    __shared__ unsigned short tile[64][72];
#pragma unroll
    for (int i = 0; i < 2; ++i) {
        int e = t + i * 256;
        int r = e >> 3, c8 = (e & 7) * 8;
        us8 v = *(const us8*)&vb[((size_t)bh * SEQ + s0 + r) * HD + c8];
        *(us8*)&tile[r][c8] = v;
    }
    __syncthreads();
#pragma unroll
    for (int i = 0; i < 2; ++i) {
        int e = t + i * 256;
        int d = e >> 3, c8 = (e & 7) * 8;
        us8 pk;
#pragma unroll
        for (int j = 0; j < 8; ++j) pk[j] = tile[c8 + j][d];
        *(us8*)&vt[((size_t)bh * HD + d) * SEQ + s0 + c8] = pk;
    }
}

// ---------------------------------------------------------------------------
// MFMA flash attention. Block = 128 thr (2 waves x 32 q-rows), 64-q tile.
// KV tiles of 64 staged via global_load_lds into XOR-chunk-swizzled linear LDS
// (chunk' = chunk ^ (row&7); source pre-swizzled per rule #21).
// Q frags in registers; P does one LDS round-trip per wave.
__global__ __launch_bounds__(128)
void attn_mfma(const unsigned short* __restrict__ qg,   // [bh][s][64], pre-scaled
               const unsigned short* __restrict__ kg,   // [bh][s][64]
               const unsigned short* __restrict__ vtg,  // [bh][d][SEQ]
               unsigned short* __restrict__ o_cond, unsigned short* __restrict__ o_img)
{
    const int q0  = blockIdx.x * 64;
    const int h   = blockIdx.y;
    const int b   = blockIdx.z;
    const int bh  = b * NH + h;
    const int t   = threadIdx.x;
    const int wid = t >> 6;
    const int lane = t & 63;
    const int g  = lane >> 4;     // k-group
    const int fr = lane & 15;     // frag row/col

    __shared__ __align__(16) unsigned short Ks [64 * 64];   // [kv][d] swizzled
    __shared__ __align__(16) unsigned short VTs[64 * 64];   // [d][kv] swizzled
    __shared__ __align__(16) unsigned short Ps [2][32][72]; // per-wave P [q][kv]

    const unsigned short* qb  = qg  + (size_t)bh * SEQ * HD;
    const unsigned short* kb  = kg  + (size_t)bh * SEQ * HD;
    const unsigned short* vtb = vtg + (size_t)bh * HD * SEQ;

    // Q fragments in registers: rows q0 + wid*32 + mt*16 + fr
    bf16x8 Qf[2][2];
#pragma unroll
    for (int mt = 0; mt < 2; ++mt)
#pragma unroll
        for (int kc = 0; kc < 2; ++kc)
            Qf[mt][kc] = *(const bf16x8*)&qb[(size_t)(q0 + wid * 32 + mt * 16 + fr) * HD
                                             + kc * 32 + g * 8];

    f32x4 O[2][4] = {};
    float mrow[2][4], lrow[2][4];
#pragma unroll
    for (int mt = 0; mt < 2; ++mt)
#pragma unroll
        for (int rg = 0; rg < 4; ++rg) { mrow[mt][rg] = -3e38f; lrow[mt][rg] = 0.f; }

    for (int tile = 0; tile < SEQ / 64; ++tile) {
        __syncthreads();   // prior tile's frag reads done
        // stage K and VT tiles (512 x 16B chunks each, 4 per thread)
#pragma unroll
        for (int i = 0; i < 4; ++i) {
            int ch = t + i * 128;                 // chunk = wavebase + lane
            int r = ch >> 3, c = ch & 7;
            int cs = c ^ (r & 7);                 // pre-swizzled source chunk
            gload_lds16(kb  + (size_t)(tile * 64 + r) * HD + cs * 8,
                        Ks  + ((i * 128 + wid * 64) << 3));
            gload_lds16(vtb + (size_t)r * SEQ + tile * 64 + cs * 8,
                        VTs + ((i * 128 + wid * 64) << 3));
        }
        __syncthreads();

        // S = Q K^T  (rows q, cols kv)
        f32x4 S[2][4] = {};
#pragma unroll
        for (int kc = 0; kc < 2; ++kc)
#pragma unroll
            for (int nt = 0; nt < 4; ++nt) {
                int r = fr + 16 * nt;
                bf16x8 kf = *(const bf16x8*)&Ks[r * 64 + (((g + 4 * kc) ^ (r & 7)) * 8)];
#pragma unroll
                for (int mt = 0; mt < 2; ++mt)
                    S[mt][nt] = __builtin_amdgcn_mfma_f32_16x16x32_bf16(
                        Qf[mt][kc], kf, S[mt][nt], 0, 0, 0);
            }

        // online softmax (wave-parallel: xor-shuffles over the 16 col-lanes)
#pragma unroll
        for (int mt = 0; mt < 2; ++mt) {
            float al[4];
#pragma unroll
            for (int rg = 0; rg < 4; ++rg) {
                float tm = fmaxf(fmaxf(S[mt][0][rg], S[mt][1][rg]),
                                 fmaxf(S[mt][2][rg], S[mt][3][rg]));
#pragma unroll
                for (int off = 1; off < 16; off <<= 1) tm = fmaxf(tm, __shfl_xor(tm, off));
                float mn = fmaxf(mrow[mt][rg], tm);
                al[rg] = __expf(mrow[mt][rg] - mn);
                mrow[mt][rg] = mn;
            }
#pragma unroll
            for (int rg = 0; rg < 4; ++rg) {
#pragma unroll
                for (int nt = 0; nt < 4; ++nt)
                    S[mt][nt][rg] = __expf(S[mt][nt][rg] - mrow[mt][rg]);
                float s0 = S[mt][0][rg] + S[mt][1][rg] + S[mt][2][rg] + S[mt][3][rg];
#pragma unroll
                for (int off = 1; off < 16; off <<= 1) s0 += __shfl_xor(s0, off);
                lrow[mt][rg] = al[rg] * lrow[mt][rg] + s0;
            }
#pragma unroll
            for (int dt = 0; dt < 4; ++dt)
#pragma unroll
                for (int rg = 0; rg < 4; ++rg) O[mt][dt][rg] *= al[rg];
            // write P (bf16) to this wave's private LDS region
#pragma unroll
            for (int nt = 0; nt < 4; ++nt)
#pragma unroll
                for (int rg = 0; rg < 4; ++rg)
                    Ps[wid][mt * 16 + 4 * g + rg][16 * nt + fr] = f2bf(S[mt][nt][rg]);
        }

        // O += P @ V   (B-operand = VT rows d)
#pragma unroll
        for (int kc = 0; kc < 2; ++kc) {
            bf16x8 Pf[2];
#pragma unroll
            for (int mt = 0; mt < 2; ++mt)
                Pf[mt] = *(const bf16x8*)&Ps[wid][mt * 16 + fr][kc * 32 + g * 8];
#pragma unroll
            for (int dt = 0; dt < 4; ++dt) {
                int r = fr + 16 * dt;
                bf16x8 vf = *(const bf16x8*)&VTs[r * 64 + (((g + 4 * kc) ^ (r & 7)) * 8)];
#pragma unroll
                for (int mt = 0; mt < 2; ++mt)
                    O[mt][dt] = __builtin_amdgcn_mfma_f32_16x16x32_bf16(
                        Pf[mt], vf, O[mt][dt], 0, 0, 0);
            }
        }
    }

    // epilogue: divide by l, store bf16 into [token][h*64+d]
#pragma unroll
    for (int mt = 0; mt < 2; ++mt)
#pragma unroll
        for (int rg = 0; rg < 4; ++rg) {
            const int s_tok = q0 + wid * 32 + mt * 16 + 4 * g + rg;
            const float linv = 1.0f / lrow[mt][rg];
#pragma unroll
            for (int dt = 0; dt < 4; ++dt) {
                unsigned short pv = f2bf(O[mt][dt][rg] * linv);
                const int col = h * HD + 16 * dt + fr;
                if (s_tok < LC) o_cond[((size_t)b * LC + s_tok) * HDIM + col] = pv;
                else            o_img [((size_t)b * LI + (s_tok - LC)) * HDIM + col] = pv;
            }
        }
}

// ---------------------------------------------------------------------------
extern "C" void kernel_launch(void* const* d_in, const int* in_sizes, int n_in,
                              void* d_out, int out_size, void* d_ws, size_t ws_size,
                              hipStream_t stream)
{
    const float* image_tokens = (const float*)d_in[0];
    const float* cond_tokens  = (const float*)d_in[1];
    const float* icos  = (const float*)d_in[2];
    const float* isin  = (const float*)d_in[3];
    const float* ccos  = (const float*)d_in[4];
    const float* csin  = (const float*)d_in[5];
    const float* img_n1w  = (const float*)d_in[6];
    const float* cond_n1w = (const float*)d_in[7];
    const float* img_qkv_w  = (const float*)d_in[8];
    const float* img_qkv_b  = (const float*)d_in[9];
    const float* cond_qkv_w = (const float*)d_in[10];
    const float* cond_qkv_b = (const float*)d_in[11];
    const float* img_qn  = (const float*)d_in[12];
    const float* img_kn  = (const float*)d_in[13];
    const float* cond_qn = (const float*)d_in[14];
    const float* cond_kn = (const float*)d_in[15];
    const float* img_out_w  = (const float*)d_in[16];
    const float* img_out_b  = (const float*)d_in[17];
    const float* cond_out_w = (const float*)d_in[18];
    const float* cond_out_b = (const float*)d_in[19];
    const float* img_n2w  = (const float*)d_in[20];
    const float* cond_n2w = (const float*)d_in[21];
    const float* img_w1 = (const float*)d_in[22];
    const float* img_b1 = (const float*)d_in[23];
    const float* img_w2 = (const float*)d_in[24];
    const float* img_b2 = (const float*)d_in[25];
    const float* img_w3 = (const float*)d_in[26];
    const float* img_b3 = (const float*)d_in[27];
    const float* cond_w1 = (const float*)d_in[28];
    const float* cond_b1 = (const float*)d_in[29];
    const float* cond_w2 = (const float*)d_in[30];
    const float* cond_b2 = (const float*)d_in[31];
    const float* cond_w3 = (const float*)d_in[32];
    const float* cond_b3 = (const float*)d_in[33];
    const float* alpha = (const float*)d_in[34];
    const float* beta  = (const float*)d_in[35];

    float* out_img  = (float*)d_out;
    float* out_cond = (float*)d_out + (size_t)BB * LI * HDIM;

    // Arena (f32 index units). Peak ~93.3 MB, proven in R1/R2.
    float* ws = (float*)d_ws;
    unsigned short* wslot   = (unsigned short*)(ws);             // bf16 weight slot (8.39 MB)
    unsigned short* xn_img  = (unsigned short*)(ws + 2097152);
    unsigned short* xn_cond = (unsigned short*)(ws + 3145728);
    float* qkv_img  = ws + 3407872;                              // 2048x3072 f32
    float* qkv_cond = ws + 9699328;                              //  512x3072 f32
    unsigned short* o_cond = (unsigned short*)(ws + 3407872);    // reuse qkv after prep
    unsigned short* o_img  = o_cond + 512 * 1024;
    float* t2_cond = ws + 4718592;
    float* t2_img  = ws + 4718592 + 524288;
    unsigned short* n2_cond = (unsigned short*)(ws + 7340032);
    unsigned short* n2_img  = n2_cond + 512 * 1024;
    float* h1 = ws + 8650752;                                    // MLP gate (overlaps q/k/v, dead then)
    unsigned short* qb  = (unsigned short*)(ws + 11272192);      // [bh][s][64] bf16
    unsigned short* kb  = (unsigned short*)(ws + 12582912);
    unsigned short* vb  = (unsigned short*)(ws + 13893632);
    unsigned short* vtb = (unsigned short*)(ws + 15204352);      // [bh][d][SEQ] bf16
    unsigned short* hbf = (unsigned short*)(ws + 19136512);

    auto cvt = [&](const float* src, unsigned short* dst, int n) {
        int n4 = n >> 2;
        int blocks = (n4 + 255) / 256; if (blocks > 2048) blocks = 2048;
        cvt_f32_bf16<<<blocks, 256, 0, stream>>>(src, dst, n4);
    };

    // 1. norm1 -> bf16
    rmsnorm_rows<unsigned short><<<BB * LI, 256, 0, stream>>>(image_tokens, img_n1w, xn_img);
    rmsnorm_rows<unsigned short><<<BB * LC, 256, 0, stream>>>(cond_tokens, cond_n1w, xn_cond);

    // 2. qkv projections
    cvt(img_qkv_w, wslot, 3 * HDIM * HDIM);
    gemm_bf16<0, float><<<dim3(3 * HDIM / 128, BB * LI / 128), 256, 0, stream>>>(
        xn_img, wslot, img_qkv_b, qkv_img, BB * LI, 3 * HDIM, HDIM, nullptr, nullptr, nullptr);
    cvt(cond_qkv_w, wslot, 3 * HDIM * HDIM);
    gemm_bf16<0, float><<<dim3(3 * HDIM / 128, BB * LC / 128), 256, 0, stream>>>(
        xn_cond, wslot, cond_qkv_b, qkv_cond, BB * LC, 3 * HDIM, HDIM, nullptr, nullptr, nullptr);

    // 3. per-head norm + rope -> bf16 q/k/v ; transpose v
    qkv_prep<<<dim3(NH, SEQ, BB), 64, 0, stream>>>(
        qkv_img, qkv_cond, img_qn, img_kn, cond_qn, cond_kn,
        icos, isin, ccos, csin, qb, kb, vb);
    transpose_v<<<dim3(SEQ / 64, BB * NH), 256, 0, stream>>>(vb, vtb);

    // 4. MFMA flash attention -> bf16 o
    attn_mfma<<<dim3(SEQ / 64, NH, BB), 128, 0, stream>>>(qb, kb, vtb, o_cond, o_img);

    // 5. output projections + residual
    cvt(cond_out_w, wslot, HDIM * HDIM);
    gemm_bf16<1, float><<<dim3(HDIM / 128, BB * LC / 128), 256, 0, stream>>>(
        o_cond, wslot, cond_out_b, t2_cond, BB * LC, HDIM, HDIM, cond_tokens, nullptr, nullptr);
    cvt(img_out_w, wslot, HDIM * HDIM);
    gemm_bf16<1, float><<<dim3(HDIM / 128, BB * LI / 128), 256, 0, stream>>>(
        o_img, wslot, img_out_b, t2_img, BB * LI, HDIM, HDIM, image_tokens, alpha, nullptr);

    // 6. norm2 -> bf16
    rmsnorm_rows<unsigned short><<<BB * LC, 256, 0, stream>>>(t2_cond, cond_n2w, n2_cond);
    rmsnorm_rows<unsigned short><<<BB * LI, 256, 0, stream>>>(t2_img, img_n2w, n2_img);

    // 7. cond MLP
    cvt(cond_w1, wslot, MLPD * HDIM);
    gemm_bf16<0, float><<<dim3(MLPD / 128, BB * LC / 128), 256, 0, stream>>>(
        n2_cond, wslot, cond_b1, h1, BB * LC, MLPD, HDIM, nullptr, nullptr, nullptr);
    cvt(cond_w2, wslot, MLPD * HDIM);
    gemm_bf16<2, unsigned short><<<dim3(MLPD / 128, BB * LC / 128), 256, 0, stream>>>(
        n2_cond, wslot, cond_b2, hbf, BB * LC, MLPD, HDIM, nullptr, nullptr, h1);
    cvt(cond_w3, wslot, HDIM * MLPD);
    gemm_bf16<1, float><<<dim3(HDIM / 128, BB * LC / 128), 256, 0, stream>>>(
        hbf, wslot, cond_b3, out_cond, BB * LC, HDIM, MLPD, t2_cond, nullptr, nullptr);

    // 8. img MLP (beta-scaled)
    cvt(img_w1, wslot, MLPD * HDIM);
    gemm_bf16<0, float><<<dim3(MLPD / 128, BB * LI / 128), 256, 0, stream>>>(
        n2_img, wslot, img_b1, h1, BB * LI, MLPD, HDIM, nullptr, nullptr, nullptr);
    cvt(img_w2, wslot, MLPD * HDIM);
    gemm_bf16<2, unsigned short><<<dim3(MLPD / 128, BB * LI / 128), 256, 0, stream>>>(
        n2_img, wslot, img_b2, hbf, BB * LI, MLPD, HDIM, nullptr, nullptr, h1);
    cvt(img_w3, wslot, HDIM * MLPD);
    gemm_bf16<1, float><<<dim3(HDIM / 128, BB * LI / 128), 256, 0, stream>>>(
        hbf, wslot, img_b3, out_img, BB * LI, HDIM, MLPD, t2_img, beta, nullptr);
}

// Round 4
// 321.668 us; speedup vs baseline: 11.0655x; 1.6823x over previous
//
#include <hip/hip_runtime.h>
#include <hip/hip_bf16.h>

// Problem constants
#define BB   2
#define LI   1024
#define LC   256
#define SEQ  1280      // LC + LI
#define HDIM 1024
#define NH   16
#define HD   64
#define MLPD 4096
#define EPS  1e-6f
#define MROWS 2560     // 2048 img rows then 512 cond rows
#define MTI  16        // img M-tiles (BM=128)
#define MTT  20        // total M-tiles (16 img + 4 cond)

typedef __bf16 bf16x8 __attribute__((ext_vector_type(8)));
typedef float f32x4 __attribute__((ext_vector_type(4)));
typedef unsigned short us4 __attribute__((ext_vector_type(4)));
typedef unsigned short us8 __attribute__((ext_vector_type(8)));

static __device__ __forceinline__ unsigned short f2bf(float f) {
    unsigned int u = __builtin_bit_cast(unsigned int, f);
    u += 0x7fffu + ((u >> 16) & 1u);
    return (unsigned short)(u >> 16);
}
static __device__ __forceinline__ float bf2f(unsigned short h) {
    unsigned int u = ((unsigned int)h) << 16;
    return __builtin_bit_cast(float, u);
}

// async global->LDS, 16B per lane. LDS dst = wave-uniform base + lane*16.
static __device__ __forceinline__ void gload_lds16(const void* g, void* l) {
    __builtin_amdgcn_global_load_lds((__attribute__((address_space(1))) void*)(g),
                                     (__attribute__((address_space(3))) void*)(l),
                                     16, 0, 0);
}

// ---------------------------------------------------------------------------
// One-shot weight pack: 8 segments. seg 0/1 interleave w1/w2 (16-col groups)
// into pair layout [8192][1024]; others plain f32->bf16 cvt.
__global__ __launch_bounds__(256)
void pack_weights(const float* __restrict__ w1i, const float* __restrict__ w2i,
                  const float* __restrict__ w1c, const float* __restrict__ w2c,
                  const float* __restrict__ w3i, const float* __restrict__ w3c,
                  const float* __restrict__ wqi, const float* __restrict__ wqc,
                  const float* __restrict__ woi, const float* __restrict__ woc,
                  unsigned short* __restrict__ wpi, unsigned short* __restrict__ wpc,
                  unsigned short* __restrict__ w3bi, unsigned short* __restrict__ w3bc,
                  unsigned short* __restrict__ wqbi, unsigned short* __restrict__ wqbc,
                  unsigned short* __restrict__ wobi, unsigned short* __restrict__ wobc)
{
    const int seg = blockIdx.y;
    const float* s0 = nullptr; const float* s1 = nullptr;
    unsigned short* dst = nullptr; int n4 = 0; bool pair = false;
    switch (seg) {
        case 0: pair = true; s0 = w1i; s1 = w2i; dst = wpi;  n4 = 8388608 / 4; break;
        case 1: pair = true; s0 = w1c; s1 = w2c; dst = wpc;  n4 = 8388608 / 4; break;
        case 2: s0 = w3i; dst = w3bi; n4 = 4194304 / 4; break;
        case 3: s0 = w3c; dst = w3bc; n4 = 4194304 / 4; break;
        case 4: s0 = wqi; dst = wqbi; n4 = 3145728 / 4; break;
        case 5: s0 = wqc; dst = wqbc; n4 = 3145728 / 4; break;
        case 6: s0 = woi; dst = wobi; n4 = 1048576 / 4; break;
        case 7: s0 = woc; dst = wobc; n4 = 1048576 / 4; break;
    }
    for (int i = blockIdx.x * 256 + threadIdx.x; i < n4; i += gridDim.x * 256) {
        float4 v;
        if (pair) {
            int p  = i >> 8;          // phys row (256 float4 per 1024-row)
            int k4 = i & 255;
            int g = p >> 4, r = p & 15;
            const float* s = (g & 1) ? s1 : s0;
            v = *(const float4*)&s[((size_t)((g >> 1) * 16 + r)) * 1024 + k4 * 4];
        } else {
            v = ((const float4*)s0)[i];
        }
        us4 o = { f2bf(v.x), f2bf(v.y), f2bf(v.z), f2bf(v.w) };
        ((us4*)dst)[i] = o;
    }
}

// ---------------------------------------------------------------------------
// norm1: rows 0..2047 img, 2048..2559 cond -> xn bf16 [2560][1024]
__global__ __launch_bounds__(256)
void rmsnorm1(const float* __restrict__ img, const float* __restrict__ cond,
              const float* __restrict__ wi, const float* __restrict__ wc,
              unsigned short* __restrict__ xn)
{
    const int row = blockIdx.x;
    const int t   = threadIdx.x;
    const float* x = (row < 2048) ? img + (size_t)row * HDIM
                                  : cond + (size_t)(row - 2048) * HDIM;
    const float* w = (row < 2048) ? wi : wc;
    float4 v = ((const float4*)x)[t];
    float ss = v.x*v.x + v.y*v.y + v.z*v.z + v.w*v.w;
    for (int o = 32; o > 0; o >>= 1) ss += __shfl_xor(ss, o);
    __shared__ float red[4];
    if ((t & 63) == 0) red[t >> 6] = ss;
    __syncthreads();
    float inv = rsqrtf((red[0]+red[1]+red[2]+red[3]) * (1.0f / HDIM) + EPS);
    float4 wv = ((const float4*)w)[t];
    us4 pk = { f2bf(v.x*inv*wv.x), f2bf(v.y*inv*wv.y),
               f2bf(v.z*inv*wv.z), f2bf(v.w*inv*wv.w) };
    *(us4*)&xn[(size_t)row * HDIM + t * 4] = pk;
}

// norm2 fused residual: val = tok + sc*op ; rmsnorm -> n2 bf16
__global__ __launch_bounds__(256)
void rmsnorm2(const float* __restrict__ img_tok, const float* __restrict__ cond_tok,
              const float* __restrict__ op, const float* __restrict__ wi,
              const float* __restrict__ wc, const float* __restrict__ alpha,
              unsigned short* __restrict__ n2)
{
    const int row = blockIdx.x;
    const int t   = threadIdx.x;
    const bool img = row < 2048;
    const float sc = img ? alpha[0] : 1.0f;
    const float* tok = img ? img_tok + (size_t)row * HDIM
                           : cond_tok + (size_t)(row - 2048) * HDIM;
    const float* w = img ? wi : wc;
    float4 tv = ((const float4*)tok)[t];
    float4 ov = ((const float4*)(op + (size_t)row * HDIM))[t];
    float4 v = { tv.x + sc*ov.x, tv.y + sc*ov.y, tv.z + sc*ov.z, tv.w + sc*ov.w };
    float ss = v.x*v.x + v.y*v.y + v.z*v.z + v.w*v.w;
    for (int o = 32; o > 0; o >>= 1) ss += __shfl_xor(ss, o);
    __shared__ float red[4];
    if ((t & 63) == 0) red[t >> 6] = ss;
    __syncthreads();
    float inv = rsqrtf((red[0]+red[1]+red[2]+red[3]) * (1.0f / HDIM) + EPS);
    float4 wv = ((const float4*)w)[t];
    us4 pk = { f2bf(v.x*inv*wv.x), f2bf(v.y*inv*wv.y),
               f2bf(v.z*inv*wv.z), f2bf(v.w*inv*wv.w) };
    *(us4*)&n2[(size_t)row * HDIM + t * 4] = pk;
}

// op = bias (broadcast), per-stream bias
__global__ __launch_bounds__(256)
void op_init(const float* __restrict__ bi, const float* __restrict__ bc,
             float* __restrict__ op)
{
    const int row = blockIdx.x, t = threadIdx.x;
    const float* b = (row < 2048) ? bi : bc;
    ((float4*)(op + (size_t)row * HDIM))[t] = ((const float4*)b)[t];
}

// out = tok + sa*op + sm*b3   (split-K down-proj accumulates sm*acc on top)
__global__ __launch_bounds__(256)
void down_init(const float* __restrict__ img_tok, const float* __restrict__ cond_tok,
               const float* __restrict__ op, const float* __restrict__ b3i,
               const float* __restrict__ b3c, const float* __restrict__ alpha,
               const float* __restrict__ beta, float* __restrict__ out)
{
    const int row = blockIdx.x, t = threadIdx.x;
    const bool img = row < 2048;
    const float sa = img ? alpha[0] : 1.0f;
    const float sm = img ? beta[0]  : 1.0f;
    const float* tok = img ? img_tok + (size_t)row * HDIM
                           : cond_tok + (size_t)(row - 2048) * HDIM;
    const float* b3 = img ? b3i : b3c;
    float4 tv = ((const float4*)tok)[t];
    float4 ov = ((const float4*)(op + (size_t)row * HDIM))[t];
    float4 bv = ((const float4*)b3)[t];
    float4 o4 = { tv.x + sa*ov.x + sm*bv.x, tv.y + sa*ov.y + sm*bv.y,
                  tv.z + sa*ov.z + sm*bv.z, tv.w + sa*ov.w + sm*bv.w };
    ((float4*)(out + (size_t)row * HDIM))[t] = o4;
}

// ---------------------------------------------------------------------------
// Grouped QKV GEMM (BM=128,BN=128,K=1024): A=xn [2560][1024]; W per group.
// Scatter epilogue -> qh/kh/vh [b*NH+h][SEQ][64] bf16 (+bias).
__global__ __launch_bounds__(256)
void qkv_gemm(const unsigned short* __restrict__ xn,
              const unsigned short* __restrict__ wqi, const unsigned short* __restrict__ wqc,
              const float* __restrict__ bi, const float* __restrict__ bc,
              unsigned short* __restrict__ qh, unsigned short* __restrict__ kh,
              unsigned short* __restrict__ vh)
{
    __shared__ __align__(16) unsigned short As[128][32];
    __shared__ __align__(16) unsigned short Ws[128][32];

    const int mt = blockIdx.x;
    const bool img = mt < MTI;
    const int row0 = img ? mt * 128 : 2048 + (mt - MTI) * 128;      // global A row
    const int grow0 = img ? mt * 128 : (mt - MTI) * 128;            // group-local
    const unsigned short* W = img ? wqi : wqc;
    const float* bias = img ? bi : bc;
    const int bn = blockIdx.y * 128;

    const int t = threadIdx.x, lane = t & 63, wid = t >> 6;
    const int wm = wid >> 1, wn = wid & 1;
    const int srow = (wid << 5) + (lane >> 2);
    const int scol = (lane & 3) << 3;
    const unsigned short* Ag0 = xn + (size_t)(row0 + srow)      * HDIM + scol;
    const unsigned short* Ag1 = xn + (size_t)(row0 + srow + 16) * HDIM + scol;
    const unsigned short* Wg0 = W  + (size_t)(bn + srow)        * HDIM + scol;
    const unsigned short* Wg1 = W  + (size_t)(bn + srow + 16)   * HDIM + scol;
    unsigned short* lA0 = &As[(wid << 5)     ][0];
    unsigned short* lA1 = &As[(wid << 5) + 16][0];
    unsigned short* lW0 = &Ws[(wid << 5)     ][0];
    unsigned short* lW1 = &Ws[(wid << 5) + 16][0];

    const int fr = lane & 15, kg = lane >> 4, ko = kg << 3;
    f32x4 acc[4][4] = {};

    for (int k0 = 0; k0 < HDIM; k0 += 32) {
        __syncthreads();
        gload_lds16(Ag0 + k0, lA0);
        gload_lds16(Ag1 + k0, lA1);
        gload_lds16(Wg0 + k0, lW0);
        gload_lds16(Wg1 + k0, lW1);
        __syncthreads();
        bf16x8 aF[4], bF[4];
#pragma unroll
        for (int m = 0; m < 4; ++m) aF[m] = *(const bf16x8*)&As[wm*64 + m*16 + fr][ko];
#pragma unroll
        for (int n = 0; n < 4; ++n) bF[n] = *(const bf16x8*)&Ws[wn*64 + n*16 + fr][ko];
#pragma unroll
        for (int m = 0; m < 4; ++m)
#pragma unroll
            for (int n = 0; n < 4; ++n)
                acc[m][n] = __builtin_amdgcn_mfma_f32_16x16x32_bf16(aF[m], bF[n], acc[m][n], 0,0,0);
    }

#pragma unroll
    for (int n = 0; n < 4; ++n) {
        const int gc = bn + wn*64 + n*16 + fr;            // 0..3071
        const int which = gc >> 10;                       // 0 q / 1 k / 2 v
        const int h = (gc >> 6) & 15, d = gc & 63;
        unsigned short* dst = which == 0 ? qh : (which == 1 ? kh : vh);
        const float bv = bias[gc];
#pragma unroll
        for (int m = 0; m < 4; ++m) {
#pragma unroll
            for (int j = 0; j < 4; ++j) {
                const int gl = grow0 + wm*64 + m*16 + (kg << 2) + j;   // group row
                int b, s;
                if (img) { b = gl >> 10; s = LC + (gl & 1023); }
                else     { b = gl >> 8;  s = gl & 255; }
                dst[(((size_t)(b*NH + h)) * SEQ + s) * HD + d] = f2bf(acc[m][n][j] + bv);
            }
        }
    }
}

// ---------------------------------------------------------------------------
// Grouped pair GEMM (BM=128,BN=128 over N=8192 phys): swiglu epilogue -> hbf.
__global__ __launch_bounds__(256)
void pair_gemm(const unsigned short* __restrict__ n2,
               const unsigned short* __restrict__ wpi, const unsigned short* __restrict__ wpc,
               const float* __restrict__ b1i, const float* __restrict__ b2i,
               const float* __restrict__ b1c, const float* __restrict__ b2c,
               unsigned short* __restrict__ hbf)
{
    __shared__ __align__(16) unsigned short As[128][32];
    __shared__ __align__(16) unsigned short Ws[128][32];

    const int mt = blockIdx.x;
    const bool img = mt < MTI;
    const int row0 = img ? mt * 128 : 2048 + (mt - MTI) * 128;
    const unsigned short* W = img ? wpi : wpc;
    const float* b1 = img ? b1i : b1c;
    const float* b2 = img ? b2i : b2c;
    const int x = blockIdx.y;              // phys col tile 0..63
    const int bn = x * 128;

    const int t = threadIdx.x, lane = t & 63, wid = t >> 6;
    const int wm = wid >> 1, wn = wid & 1;
    const int srow = (wid << 5) + (lane >> 2);
    const int scol = (lane & 3) << 3;
    const unsigned short* Ag0 = n2 + (size_t)(row0 + srow)      * HDIM + scol;
    const unsigned short* Ag1 = n2 + (size_t)(row0 + srow + 16) * HDIM + scol;
    const unsigned short* Wg0 = W  + (size_t)(bn + srow)        * HDIM + scol;
    const unsigned short* Wg1 = W  + (size_t)(bn + srow + 16)   * HDIM + scol;
    unsigned short* lA0 = &As[(wid << 5)     ][0];
    unsigned short* lA1 = &As[(wid << 5) + 16][0];
    unsigned short* lW0 = &Ws[(wid << 5)     ][0];
    unsigned short* lW1 = &Ws[(wid << 5) + 16][0];

    const int fr = lane & 15, kg = lane >> 4, ko = kg << 3;
    f32x4 acc[4][4] = {};

    for (int k0 = 0; k0 < HDIM; k0 += 32) {
        __syncthreads();
        gload_lds16(Ag0 + k0, lA0);
        gload_lds16(Ag1 + k0, lA1);
        gload_lds16(Wg0 + k0, lW0);
        gload_lds16(Wg1 + k0, lW1);
        __syncthreads();
        bf16x8 aF[4], bF[4];
#pragma unroll
        for (int m = 0; m < 4; ++m) aF[m] = *(const bf16x8*)&As[wm*64 + m*16 + fr][ko];
#pragma unroll
        for (int n = 0; n < 4; ++n) bF[n] = *(const bf16x8*)&Ws[wn*64 + n*16 + fr][ko];
#pragma unroll
        for (int m = 0; m < 4; ++m)
#pragma unroll
            for (int n = 0; n < 4; ++n)
                acc[m][n] = __builtin_amdgcn_mfma_f32_16x16x32_bf16(aF[m], bF[n], acc[m][n], 0,0,0);
    }

    // epilogue: pairs (nt=0,1) and (nt=2,3): logical col lc = (4x+2wn+p)*16+fr
#pragma unroll
    for (int p = 0; p < 2; ++p) {
        const int lc = (4*x + 2*wn + p) * 16 + fr;        // 0..4095
        const float b1v = b1[lc], b2v = b2[lc];
#pragma unroll
        for (int m = 0; m < 4; ++m) {
#pragma unroll
            for (int j = 0; j < 4; ++j) {
                const int row = row0 + wm*64 + m*16 + (kg << 2) + j;
                float g1 = acc[m][2*p    ][j] + b1v;
                float g2 = acc[m][2*p + 1][j] + b2v;
                float hv = (g1 / (1.0f + __expf(-g1))) * g2;
                hbf[(size_t)row * MLPD + lc] = f2bf(hv);
            }
        }
    }
}

// ---------------------------------------------------------------------------
// Grouped N-narrow GEMM (BM=128,BN=64) with split-K; atomic f32 accumulate.
// out rows shared space (img 0..2047, cond 2048..2559); per-group W and scale.
__global__ __launch_bounds__(256)
void nk_gemm(const unsigned short* __restrict__ A, int K,
             const unsigned short* __restrict__ Wimg, const unsigned short* __restrict__ Wcond,
             float* __restrict__ out, int kchunk,
             const float* __restrict__ sci, const float* __restrict__ scc)
{
    __shared__ __align__(16) unsigned short As[128][32];
    __shared__ __align__(16) unsigned short Ws[64][32];

    const int mt = blockIdx.x;
    const bool img = mt < MTI;
    const int row0 = img ? mt * 128 : 2048 + (mt - MTI) * 128;
    const unsigned short* W = img ? Wimg : Wcond;
    const float sc = img ? (sci ? sci[0] : 1.0f) : (scc ? scc[0] : 1.0f);
    const int bn = blockIdx.y * 64;
    const int kbase = blockIdx.z * kchunk;

    const int t = threadIdx.x, lane = t & 63, wid = t >> 6;
    const int srowA = (wid << 5) + (lane >> 2);
    const int srowW = (wid << 4) + (lane >> 2);
    const int scol  = (lane & 3) << 3;
    const unsigned short* Ag0 = A + (size_t)(row0 + srowA)      * K + kbase + scol;
    const unsigned short* Ag1 = A + (size_t)(row0 + srowA + 16) * K + kbase + scol;
    const unsigned short* Wg  = W + (size_t)(bn + srowW)        * K + kbase + scol;
    unsigned short* lA0 = &As[(wid << 5)     ][0];
    unsigned short* lA1 = &As[(wid << 5) + 16][0];
    unsigned short* lW  = &Ws[(wid << 4)     ][0];

    const int fr = lane & 15, kg = lane >> 4, ko = kg << 3;
    f32x4 acc[2][4] = {};

    for (int k0 = 0; k0 < kchunk; k0 += 32) {
        __syncthreads();
        gload_lds16(Ag0 + k0, lA0);
        gload_lds16(Ag1 + k0, lA1);
        gload_lds16(Wg  + k0, lW);
        __syncthreads();
        bf16x8 aF[2], bF[4];
#pragma unroll
        for (int m = 0; m < 2; ++m) aF[m] = *(const bf16x8*)&As[(wid<<5) + m*16 + fr][ko];
#pragma unroll
        for (int n = 0; n < 4; ++n) bF[n] = *(const bf16x8*)&Ws[n*16 + fr][ko];
#pragma unroll
        for (int m = 0; m < 2; ++m)
#pragma unroll
            for (int n = 0; n < 4; ++n)
                acc[m][n] = __builtin_amdgcn_mfma_f32_16x16x32_bf16(aF[m], bF[n], acc[m][n], 0,0,0);
    }

#pragma unroll
    for (int n = 0; n < 4; ++n) {
        const int col = bn + n*16 + fr;
#pragma unroll
        for (int m = 0; m < 2; ++m) {
#pragma unroll
            for (int j = 0; j < 4; ++j) {
                const int row = row0 + (wid << 5) + m*16 + (kg << 2) + j;
                unsafeAtomicAdd(&out[(size_t)row * HDIM + col], sc * acc[m][n][j]);
            }
        }
    }
}

// ---------------------------------------------------------------------------
// In-place per-head RMSNorm + RoPE on qh,kh (q gets 1/8 fold). vh untouched.
__launch_bounds__(64)
__global__ void qkv_prep(unsigned short* __restrict__ qh, unsigned short* __restrict__ kh,
                         const float* __restrict__ img_qn, const float* __restrict__ img_kn,
                         const float* __restrict__ cond_qn, const float* __restrict__ cond_kn,
                         const float* __restrict__ icos, const float* __restrict__ isin,
                         const float* __restrict__ ccos, const float* __restrict__ csin)
{
    const int h = blockIdx.x, s = blockIdx.y, b = blockIdx.z;
    const int d = threadIdx.x;
    const float *qw, *kw, *cs, *sn;
    if (s < LC) { qw = cond_qn; kw = cond_kn;
                  cs = ccos + (size_t)s * HD; sn = csin + (size_t)s * HD; }
    else        { qw = img_qn; kw = img_kn;
                  cs = icos + (size_t)(s - LC) * HD; sn = isin + (size_t)(s - LC) * HD; }
    const size_t idx = (((size_t)(b*NH + h)) * SEQ + s) * HD + d;
    float qv = bf2f(qh[idx]);
    float kv = bf2f(kh[idx]);

    float sq = qv * qv;
    for (int o = 32; o > 0; o >>= 1) sq += __shfl_xor(sq, o);
    float qn = qv * rsqrtf(sq * (1.0f / HD) + EPS) * qw[d];
    float sk = kv * kv;
    for (int o = 32; o > 0; o >>= 1) sk += __shfl_xor(sk, o);
    float kn = kv * rsqrtf(sk * (1.0f / HD) + EPS) * kw[d];

    const float c = cs[d], s_ = sn[d];
    float qp = __shfl_xor(qn, 32);
    float kp = __shfl_xor(kn, 32);
    float qrot = (d < 32) ? -qp : qp;
    float krot = (d < 32) ? -kp : kp;
    qh[idx] = f2bf((qn * c + qrot * s_) * 0.125f);
    kh[idx] = f2bf(kn * c + krot * s_);
}

// ---------------------------------------------------------------------------
// 64x64 bf16 tile transpose: vh [bh][s][d] -> vt [bh][d][s]
__global__ __launch_bounds__(256)
void transpose_v(const unsigned short* __restrict__ vb, unsigned short* __restrict__ vt)
{
    const int bh = blockIdx.y;
    const int s0 = blockIdx.x * 64;
    const int t  = threadIdx.x;
    __shared__ unsigned short tile[64][72];
#pragma unroll
    for (int i = 0; i < 2; ++i) {
        int e = t + i * 256;
        int r = e >> 3, c8 = (e & 7) * 8;
        us8 v = *(const us8*)&vb[((size_t)bh * SEQ + s0 + r) * HD + c8];
        *(us8*)&tile[r][c8] = v;
    }
    __syncthreads();
#pragma unroll
    for (int i = 0; i < 2; ++i) {
        int e = t + i * 256;
        int d = e >> 3, c8 = (e & 7) * 8;
        us8 pk;
#pragma unroll
        for (int j = 0; j < 8; ++j) pk[j] = tile[c8 + j][d];
        *(us8*)&vt[((size_t)bh * HD + d) * SEQ + s0 + c8] = pk;
    }
}

// ---------------------------------------------------------------------------
// MFMA flash attention (R3-validated). o rows: img b*1024+(s-LC); cond 2048+b*256+s.
__global__ __launch_bounds__(128)
void attn_mfma(const unsigned short* __restrict__ qg,
               const unsigned short* __restrict__ kg,
               const unsigned short* __restrict__ vtg,
               unsigned short* __restrict__ o)
{
    const int q0  = blockIdx.x * 64;
    const int h   = blockIdx.y;
    const int b   = blockIdx.z;
    const int bh  = b * NH + h;
    const int t   = threadIdx.x;
    const int wid = t >> 6;
    const int lane = t & 63;
    const int g  = lane >> 4;
    const int fr = lane & 15;

    __shared__ __align__(16) unsigned short Ks [64 * 64];
    __shared__ __align__(16) unsigned short VTs[64 * 64];
    __shared__ __align__(16) unsigned short Ps [2][32][72];

    const unsigned short* qb  = qg  + (size_t)bh * SEQ * HD;
    const unsigned short* kb  = kg  + (size_t)bh * SEQ * HD;
    const unsigned short* vtb = vtg + (size_t)bh * HD * SEQ;

    bf16x8 Qf[2][2];
#pragma unroll
    for (int mt = 0; mt < 2; ++mt)
#pragma unroll
        for (int kc = 0; kc < 2; ++kc)
            Qf[mt][kc] = *(const bf16x8*)&qb[(size_t)(q0 + wid*32 + mt*16 + fr) * HD
                                             + kc*32 + g*8];

    f32x4 O[2][4] = {};
    float mrow[2][4], lrow[2][4];
#pragma unroll
    for (int mt = 0; mt < 2; ++mt)
#pragma unroll
        for (int rg = 0; rg < 4; ++rg) { mrow[mt][rg] = -3e38f; lrow[mt][rg] = 0.f; }

    for (int tile = 0; tile < SEQ / 64; ++tile) {
        __syncthreads();
#pragma unroll
        for (int i = 0; i < 4; ++i) {
            int ch = t + i * 128;
            int r = ch >> 3, c = ch & 7;
            int cs = c ^ (r & 7);
            gload_lds16(kb  + (size_t)(tile*64 + r) * HD + cs*8,
                        Ks  + ((i*128 + wid*64) << 3));
            gload_lds16(vtb + (size_t)r * SEQ + tile*64 + cs*8,
                        VTs + ((i*128 + wid*64) << 3));
        }
        __syncthreads();

        f32x4 S[2][4] = {};
#pragma unroll
        for (int kc = 0; kc < 2; ++kc)
#pragma unroll
            for (int nt = 0; nt < 4; ++nt) {
                int r = fr + 16*nt;
                bf16x8 kf = *(const bf16x8*)&Ks[r*64 + (((g + 4*kc) ^ (r & 7)) * 8)];
#pragma unroll
                for (int mt = 0; mt < 2; ++mt)
                    S[mt][nt] = __builtin_amdgcn_mfma_f32_16x16x32_bf16(
                        Qf[mt][kc], kf, S[mt][nt], 0, 0, 0);
            }

#pragma unroll
        for (int mt = 0; mt < 2; ++mt) {
            float al[4];
#pragma unroll
            for (int rg = 0; rg < 4; ++rg) {
                float tm = fmaxf(fmaxf(S[mt][0][rg], S[mt][1][rg]),
                                 fmaxf(S[mt][2][rg], S[mt][3][rg]));
#pragma unroll
                for (int off = 1; off < 16; off <<= 1) tm = fmaxf(tm, __shfl_xor(tm, off));
                float mn = fmaxf(mrow[mt][rg], tm);
                al[rg] = __expf(mrow[mt][rg] - mn);
                mrow[mt][rg] = mn;
            }
#pragma unroll
            for (int rg = 0; rg < 4; ++rg) {
#pragma unroll
                for (int nt = 0; nt < 4; ++nt)
                    S[mt][nt][rg] = __expf(S[mt][nt][rg] - mrow[mt][rg]);
                float s0 = S[mt][0][rg] + S[mt][1][rg] + S[mt][2][rg] + S[mt][3][rg];
#pragma unroll
                for (int off = 1; off < 16; off <<= 1) s0 += __shfl_xor(s0, off);
                lrow[mt][rg] = al[rg] * lrow[mt][rg] + s0;
            }
#pragma unroll
            for (int dt = 0; dt < 4; ++dt)
#pragma unroll
                for (int rg = 0; rg < 4; ++rg) O[mt][dt][rg] *= al[rg];
#pragma unroll
            for (int nt = 0; nt < 4; ++nt)
#pragma unroll
                for (int rg = 0; rg < 4; ++rg)
                    Ps[wid][mt*16 + 4*g + rg][16*nt + fr] = f2bf(S[mt][nt][rg]);
        }

#pragma unroll
        for (int kc = 0; kc < 2; ++kc) {
            bf16x8 Pf[2];
#pragma unroll
            for (int mt = 0; mt < 2; ++mt)
                Pf[mt] = *(const bf16x8*)&Ps[wid][mt*16 + fr][kc*32 + g*8];
#pragma unroll
            for (int dt = 0; dt < 4; ++dt) {
                int r = fr + 16*dt;
                bf16x8 vf = *(const bf16x8*)&VTs[r*64 + (((g + 4*kc) ^ (r & 7)) * 8)];
#pragma unroll
                for (int mt = 0; mt < 2; ++mt)
                    O[mt][dt] = __builtin_amdgcn_mfma_f32_16x16x32_bf16(
                        Pf[mt], vf, O[mt][dt], 0, 0, 0);
            }
        }
    }

#pragma unroll
    for (int mt = 0; mt < 2; ++mt)
#pragma unroll
        for (int rg = 0; rg < 4; ++rg) {
            const int s_tok = q0 + wid*32 + mt*16 + 4*g + rg;
            const float linv = 1.0f / lrow[mt][rg];
            const size_t row = (s_tok < LC) ? (size_t)(2048 + b*LC + s_tok)
                                            : (size_t)(b*LI + (s_tok - LC));
#pragma unroll
            for (int dt = 0; dt < 4; ++dt)
                o[row * HDIM + h*HD + 16*dt + fr] = f2bf(O[mt][dt][rg] * linv);
        }
}

// ---------------------------------------------------------------------------
extern "C" void kernel_launch(void* const* d_in, const int* in_sizes, int n_in,
                              void* d_out, int out_size, void* d_ws, size_t ws_size,
                              hipStream_t stream)
{
    const float* image_tokens = (const float*)d_in[0];
    const float* cond_tokens  = (const float*)d_in[1];
    const float* icos  = (const float*)d_in[2];
    const float* isin  = (const float*)d_in[3];
    const float* ccos  = (const float*)d_in[4];
    const float* csin  = (const float*)d_in[5];
    const float* img_n1w  = (const float*)d_in[6];
    const float* cond_n1w = (const float*)d_in[7];
    const float* img_qkv_w  = (const float*)d_in[8];
    const float* img_qkv_b  = (const float*)d_in[9];
    const float* cond_qkv_w = (const float*)d_in[10];
    const float* cond_qkv_b = (const float*)d_in[11];
    const float* img_qn  = (const float*)d_in[12];
    const float* img_kn  = (const float*)d_in[13];
    const float* cond_qn = (const float*)d_in[14];
    const float* cond_kn = (const float*)d_in[15];
    const float* img_out_w  = (const float*)d_in[16];
    const float* img_out_b  = (const float*)d_in[17];
    const float* cond_out_w = (const float*)d_in[18];
    const float* cond_out_b = (const float*)d_in[19];
    const float* img_n2w  = (const float*)d_in[20];
    const float* cond_n2w = (const float*)d_in[21];
    const float* img_w1 = (const float*)d_in[22];
    const float* img_b1 = (const float*)d_in[23];
    const float* img_w2 = (const float*)d_in[24];
    const float* img_b2 = (const float*)d_in[25];
    const float* img_w3 = (const float*)d_in[26];
    const float* img_b3 = (const float*)d_in[27];
    const float* cond_w1 = (const float*)d_in[28];
    const float* cond_b1 = (const float*)d_in[29];
    const float* cond_w2 = (const float*)d_in[30];
    const float* cond_b2 = (const float*)d_in[31];
    const float* cond_w3 = (const float*)d_in[32];
    const float* cond_b3 = (const float*)d_in[33];
    const float* alpha = (const float*)d_in[34];
    const float* beta  = (const float*)d_in[35];

    float* out = (float*)d_out;   // rows: img 0..2047, cond 2048..2559 (matches concat)

    // Arena (unsigned short units from base). Peak 93.3 MB <= 94.4 proven.
    unsigned short* u = (unsigned short*)d_ws;
    unsigned short* wp_i  = u + 0;          // [8192][1024] pair img
    unsigned short* wp_c  = u + 8388608;    // pair cond
    unsigned short* w3b_i = u + 16777216;   // [1024][4096]
    unsigned short* w3b_c = u + 20971520;
    unsigned short* wqb_i = u + 25165824;   // [3072][1024]
    unsigned short* wqb_c = u + 28311552;
    unsigned short* wob_i = u + 31457280;   // [1024][1024]
    unsigned short* wob_c = u + 32505856;
    const size_t A0 = 33554432;
    unsigned short* xn = u + A0;                 // [2560][1024] bf16 (dead after qkv)
    unsigned short* vt = u + A0;                 // reuse (after qkv gemm)
    unsigned short* qh = u + A0 + 2621440;       // [32][1280][64] bf16
    unsigned short* kh = u + A0 + 5242880;
    unsigned short* vh = u + A0 + 7864320;
    unsigned short* o  = u + A0 + 10485760;      // [2560][1024] bf16
    float*          op = (float*)(u + A0 + 2621440);   // [2560][1024] f32 (over qh/kh, dead)
    unsigned short* n2 = u + A0 + 7864320;       // [2560][1024] bf16 (over vh, dead)
    unsigned short* hbf = u + 25165824;          // [2560][4096] bf16 (over wq/wo + xn/vt, dead)

    // 1. pack all weights (one dispatch)
    pack_weights<<<dim3(512, 8), 256, 0, stream>>>(
        img_w1, img_w2, cond_w1, cond_w2, img_w3, cond_w3,
        img_qkv_w, cond_qkv_w, img_out_w, cond_out_w,
        wp_i, wp_c, w3b_i, w3b_c, wqb_i, wqb_c, wob_i, wob_c);

    // 2. norm1 (fused img+cond)
    rmsnorm1<<<MROWS, 256, 0, stream>>>(image_tokens, cond_tokens, img_n1w, cond_n1w, xn);

    // 3. grouped qkv GEMM -> scatter to qh/kh/vh
    qkv_gemm<<<dim3(MTT, 24), 256, 0, stream>>>(
        xn, wqb_i, wqb_c, img_qkv_b, cond_qkv_b, qh, kh, vh);

    // 4. in-place per-head norm+rope; V transpose
    qkv_prep<<<dim3(NH, SEQ, BB), 64, 0, stream>>>(
        qh, kh, img_qn, img_kn, cond_qn, cond_kn, icos, isin, ccos, csin);
    transpose_v<<<dim3(SEQ / 64, BB * NH), 256, 0, stream>>>(vh, vt);

    // 5. flash attention -> o
    attn_mfma<<<dim3(SEQ / 64, NH, BB), 128, 0, stream>>>(qh, kh, vt, o);

    // 6. out-proj: op = bias; += o @ Wo^T (grouped, split-K=2, atomic)
    op_init<<<MROWS, 256, 0, stream>>>(img_out_b, cond_out_b, op);
    nk_gemm<<<dim3(MTT, 16, 2), 256, 0, stream>>>(
        o, HDIM, wob_i, wob_c, op, HDIM / 2, nullptr, nullptr);

    // 7. norm2 fused with residual (tok + sc*op)
    rmsnorm2<<<MROWS, 256, 0, stream>>>(
        image_tokens, cond_tokens, op, img_n2w, cond_n2w, alpha, n2);

    // 8. pair GEMM (up1+up2 fused, swiglu) -> hbf
    pair_gemm<<<dim3(MTT, 64), 256, 0, stream>>>(
        n2, wp_i, wp_c, img_b1, img_b2, cond_b1, cond_b2, hbf);

    // 9. down-proj: out = tok + sa*op + sm*b3; += sm * (hbf @ W3^T) (split-K=4)
    down_init<<<MROWS, 256, 0, stream>>>(
        image_tokens, cond_tokens, op, img_b3, cond_b3, alpha, beta, out);
    nk_gemm<<<dim3(MTT, 16, 4), 256, 0, stream>>>(
        hbf, MLPD, w3b_i, w3b_c, out, MLPD / 4, beta, nullptr);
}

// Round 5
// 294.541 us; speedup vs baseline: 12.0846x; 1.0921x over previous
//
#include <hip/hip_runtime.h>
#include <hip/hip_bf16.h>

// Problem constants
#define BB   2
#define LI   1024
#define LC   256
#define SEQ  1280      // LC + LI
#define HDIM 1024
#define NH   16
#define HD   64
#define MLPD 4096
#define EPS  1e-6f
#define MROWS 2560     // 2048 img rows then 512 cond rows
#define MTI  16        // img M-tiles (BM=128)
#define MTT  20        // total M-tiles (16 img + 4 cond)

typedef __bf16 bf16x8 __attribute__((ext_vector_type(8)));
typedef float f32x4 __attribute__((ext_vector_type(4)));
typedef unsigned short us4 __attribute__((ext_vector_type(4)));
typedef unsigned short us8 __attribute__((ext_vector_type(8)));

static __device__ __forceinline__ unsigned short f2bf(float f) {
    unsigned int u = __builtin_bit_cast(unsigned int, f);
    u += 0x7fffu + ((u >> 16) & 1u);
    return (unsigned short)(u >> 16);
}
static __device__ __forceinline__ float bf2f(unsigned short h) {
    unsigned int u = ((unsigned int)h) << 16;
    return __builtin_bit_cast(float, u);
}

// async global->LDS, 16B per lane. LDS dst = wave-uniform base + lane*16.
static __device__ __forceinline__ void gload_lds16(const void* g, void* l) {
    __builtin_amdgcn_global_load_lds((__attribute__((address_space(1))) void*)(g),
                                     (__attribute__((address_space(3))) void*)(l),
                                     16, 0, 0);
}

// ---------------------------------------------------------------------------
// One-shot weight pack: 8 segments. seg 0/1 interleave w1/w2 (16-col groups)
// into pair layout [8192][1024]; others plain f32->bf16 cvt.
__global__ __launch_bounds__(256)
void pack_weights(const float* __restrict__ w1i, const float* __restrict__ w2i,
                  const float* __restrict__ w1c, const float* __restrict__ w2c,
                  const float* __restrict__ w3i, const float* __restrict__ w3c,
                  const float* __restrict__ wqi, const float* __restrict__ wqc,
                  const float* __restrict__ woi, const float* __restrict__ woc,
                  unsigned short* __restrict__ wpi, unsigned short* __restrict__ wpc,
                  unsigned short* __restrict__ w3bi, unsigned short* __restrict__ w3bc,
                  unsigned short* __restrict__ wqbi, unsigned short* __restrict__ wqbc,
                  unsigned short* __restrict__ wobi, unsigned short* __restrict__ wobc)
{
    const int seg = blockIdx.y;
    const float* s0 = nullptr; const float* s1 = nullptr;
    unsigned short* dst = nullptr; int n4 = 0; bool pair = false;
    switch (seg) {
        case 0: pair = true; s0 = w1i; s1 = w2i; dst = wpi;  n4 = 8388608 / 4; break;
        case 1: pair = true; s0 = w1c; s1 = w2c; dst = wpc;  n4 = 8388608 / 4; break;
        case 2: s0 = w3i; dst = w3bi; n4 = 4194304 / 4; break;
        case 3: s0 = w3c; dst = w3bc; n4 = 4194304 / 4; break;
        case 4: s0 = wqi; dst = wqbi; n4 = 3145728 / 4; break;
        case 5: s0 = wqc; dst = wqbc; n4 = 3145728 / 4; break;
        case 6: s0 = woi; dst = wobi; n4 = 1048576 / 4; break;
        case 7: s0 = woc; dst = wobc; n4 = 1048576 / 4; break;
    }
    for (int i = blockIdx.x * 256 + threadIdx.x; i < n4; i += gridDim.x * 256) {
        float4 v;
        if (pair) {
            int p  = i >> 8;          // phys row (256 float4 per 1024-row)
            int k4 = i & 255;
            int g = p >> 4, r = p & 15;
            const float* s = (g & 1) ? s1 : s0;
            v = *(const float4*)&s[((size_t)((g >> 1) * 16 + r)) * 1024 + k4 * 4];
        } else {
            v = ((const float4*)s0)[i];
        }
        us4 o = { f2bf(v.x), f2bf(v.y), f2bf(v.z), f2bf(v.w) };
        ((us4*)dst)[i] = o;
    }
}

// ---------------------------------------------------------------------------
// norm1: rows 0..2047 img, 2048..2559 cond -> xn bf16 [2560][1024]
__global__ __launch_bounds__(256)
void rmsnorm1(const float* __restrict__ img, const float* __restrict__ cond,
              const float* __restrict__ wi, const float* __restrict__ wc,
              unsigned short* __restrict__ xn)
{
    const int row = blockIdx.x;
    const int t   = threadIdx.x;
    const float* x = (row < 2048) ? img + (size_t)row * HDIM
                                  : cond + (size_t)(row - 2048) * HDIM;
    const float* w = (row < 2048) ? wi : wc;
    float4 v = ((const float4*)x)[t];
    float ss = v.x*v.x + v.y*v.y + v.z*v.z + v.w*v.w;
    for (int o = 32; o > 0; o >>= 1) ss += __shfl_xor(ss, o);
    __shared__ float red[4];
    if ((t & 63) == 0) red[t >> 6] = ss;
    __syncthreads();
    float inv = rsqrtf((red[0]+red[1]+red[2]+red[3]) * (1.0f / HDIM) + EPS);
    float4 wv = ((const float4*)w)[t];
    us4 pk = { f2bf(v.x*inv*wv.x), f2bf(v.y*inv*wv.y),
               f2bf(v.z*inv*wv.z), f2bf(v.w*inv*wv.w) };
    *(us4*)&xn[(size_t)row * HDIM + t * 4] = pk;
}

// norm2 fused residual: val = tok + sc*op ; rmsnorm -> n2 bf16
__global__ __launch_bounds__(256)
void rmsnorm2(const float* __restrict__ img_tok, const float* __restrict__ cond_tok,
              const float* __restrict__ op, const float* __restrict__ wi,
              const float* __restrict__ wc, const float* __restrict__ alpha,
              unsigned short* __restrict__ n2)
{
    const int row = blockIdx.x;
    const int t   = threadIdx.x;
    const bool img = row < 2048;
    const float sc = img ? alpha[0] : 1.0f;
    const float* tok = img ? img_tok + (size_t)row * HDIM
                           : cond_tok + (size_t)(row - 2048) * HDIM;
    const float* w = img ? wi : wc;
    float4 tv = ((const float4*)tok)[t];
    float4 ov = ((const float4*)(op + (size_t)row * HDIM))[t];
    float4 v = { tv.x + sc*ov.x, tv.y + sc*ov.y, tv.z + sc*ov.z, tv.w + sc*ov.w };
    float ss = v.x*v.x + v.y*v.y + v.z*v.z + v.w*v.w;
    for (int o = 32; o > 0; o >>= 1) ss += __shfl_xor(ss, o);
    __shared__ float red[4];
    if ((t & 63) == 0) red[t >> 6] = ss;
    __syncthreads();
    float inv = rsqrtf((red[0]+red[1]+red[2]+red[3]) * (1.0f / HDIM) + EPS);
    float4 wv = ((const float4*)w)[t];
    us4 pk = { f2bf(v.x*inv*wv.x), f2bf(v.y*inv*wv.y),
               f2bf(v.z*inv*wv.z), f2bf(v.w*inv*wv.w) };
    *(us4*)&n2[(size_t)row * HDIM + t * 4] = pk;
}

// op = bias (broadcast), per-stream bias
__global__ __launch_bounds__(256)
void op_init(const float* __restrict__ bi, const float* __restrict__ bc,
             float* __restrict__ op)
{
    const int row = blockIdx.x, t = threadIdx.x;
    const float* b = (row < 2048) ? bi : bc;
    ((float4*)(op + (size_t)row * HDIM))[t] = ((const float4*)b)[t];
}

// out = tok + sa*op + sm*b3   (split-K down-proj accumulates sm*acc on top)
__global__ __launch_bounds__(256)
void down_init(const float* __restrict__ img_tok, const float* __restrict__ cond_tok,
               const float* __restrict__ op, const float* __restrict__ b3i,
               const float* __restrict__ b3c, const float* __restrict__ alpha,
               const float* __restrict__ beta, float* __restrict__ out)
{
    const int row = blockIdx.x, t = threadIdx.x;
    const bool img = row < 2048;
    const float sa = img ? alpha[0] : 1.0f;
    const float sm = img ? beta[0]  : 1.0f;
    const float* tok = img ? img_tok + (size_t)row * HDIM
                           : cond_tok + (size_t)(row - 2048) * HDIM;
    const float* b3 = img ? b3i : b3c;
    float4 tv = ((const float4*)tok)[t];
    float4 ov = ((const float4*)(op + (size_t)row * HDIM))[t];
    float4 bv = ((const float4*)b3)[t];
    float4 o4 = { tv.x + sa*ov.x + sm*bv.x, tv.y + sa*ov.y + sm*bv.y,
                  tv.z + sa*ov.z + sm*bv.z, tv.w + sa*ov.w + sm*bv.w };
    ((float4*)(out + (size_t)row * HDIM))[t] = o4;
}

// ---------------------------------------------------------------------------
// Grouped QKV GEMM (BM=128,BN=128,K=1024): A=xn [2560][1024]; W per group.
// Scatter epilogue: q,k -> [b*NH+h][SEQ][64]; v -> TRANSPOSED vt [b*NH+h][d][SEQ].
__global__ __launch_bounds__(256)
void qkv_gemm(const unsigned short* __restrict__ xn,
              const unsigned short* __restrict__ wqi, const unsigned short* __restrict__ wqc,
              const float* __restrict__ bi, const float* __restrict__ bc,
              unsigned short* __restrict__ qh, unsigned short* __restrict__ kh,
              unsigned short* __restrict__ vt)
{
    __shared__ __align__(16) unsigned short As[128][32];
    __shared__ __align__(16) unsigned short Ws[128][32];

    const int mt = blockIdx.x;
    const bool img = mt < MTI;
    const int row0 = img ? mt * 128 : 2048 + (mt - MTI) * 128;      // global A row
    const int grow0 = img ? mt * 128 : (mt - MTI) * 128;            // group-local
    const unsigned short* W = img ? wqi : wqc;
    const float* bias = img ? bi : bc;
    const int bn = blockIdx.y * 128;

    const int t = threadIdx.x, lane = t & 63, wid = t >> 6;
    const int wm = wid >> 1, wn = wid & 1;
    const int srow = (wid << 5) + (lane >> 2);
    const int scol = (lane & 3) << 3;
    const unsigned short* Ag0 = xn + (size_t)(row0 + srow)      * HDIM + scol;
    const unsigned short* Ag1 = xn + (size_t)(row0 + srow + 16) * HDIM + scol;
    const unsigned short* Wg0 = W  + (size_t)(bn + srow)        * HDIM + scol;
    const unsigned short* Wg1 = W  + (size_t)(bn + srow + 16)   * HDIM + scol;
    unsigned short* lA0 = &As[(wid << 5)     ][0];
    unsigned short* lA1 = &As[(wid << 5) + 16][0];
    unsigned short* lW0 = &Ws[(wid << 5)     ][0];
    unsigned short* lW1 = &Ws[(wid << 5) + 16][0];

    const int fr = lane & 15, kg = lane >> 4, ko = kg << 3;
    f32x4 acc[4][4] = {};

    for (int k0 = 0; k0 < HDIM; k0 += 32) {
        __syncthreads();
        gload_lds16(Ag0 + k0, lA0);
        gload_lds16(Ag1 + k0, lA1);
        gload_lds16(Wg0 + k0, lW0);
        gload_lds16(Wg1 + k0, lW1);
        __syncthreads();
        bf16x8 aF[4], bF[4];
#pragma unroll
        for (int m = 0; m < 4; ++m) aF[m] = *(const bf16x8*)&As[wm*64 + m*16 + fr][ko];
#pragma unroll
        for (int n = 0; n < 4; ++n) bF[n] = *(const bf16x8*)&Ws[wn*64 + n*16 + fr][ko];
#pragma unroll
        for (int m = 0; m < 4; ++m)
#pragma unroll
            for (int n = 0; n < 4; ++n)
                acc[m][n] = __builtin_amdgcn_mfma_f32_16x16x32_bf16(aF[m], bF[n], acc[m][n], 0,0,0);
    }

#pragma unroll
    for (int n = 0; n < 4; ++n) {
        const int gc = bn + wn*64 + n*16 + fr;            // 0..3071
        const int which = gc >> 10;                       // 0 q / 1 k / 2 v
        const int h = (gc >> 6) & 15, d = gc & 63;
        const float bv = bias[gc];
#pragma unroll
        for (int m = 0; m < 4; ++m) {
            const int gl0 = grow0 + wm*64 + m*16 + (kg << 2);    // group row, j=0
            int b, s0;
            if (img) { b = gl0 >> 10; s0 = LC + (gl0 & 1023); }
            else     { b = gl0 >> 8;  s0 = gl0 & 255; }
            if (which == 2) {
                // transposed V store: 4 consecutive s -> us4 pack
                us4 pk = { f2bf(acc[m][n][0] + bv), f2bf(acc[m][n][1] + bv),
                           f2bf(acc[m][n][2] + bv), f2bf(acc[m][n][3] + bv) };
                *(us4*)&vt[(((size_t)(b*NH + h)) * HD + d) * SEQ + s0] = pk;
            } else {
                unsigned short* dst = (which == 0) ? qh : kh;
#pragma unroll
                for (int j = 0; j < 4; ++j)
                    dst[(((size_t)(b*NH + h)) * SEQ + s0 + j) * HD + d] = f2bf(acc[m][n][j] + bv);
            }
        }
    }
}

// ---------------------------------------------------------------------------
// Grouped pair GEMM (BM=128,BN=128 over N=8192 phys): swiglu epilogue -> hbf.
__global__ __launch_bounds__(256)
void pair_gemm(const unsigned short* __restrict__ n2,
               const unsigned short* __restrict__ wpi, const unsigned short* __restrict__ wpc,
               const float* __restrict__ b1i, const float* __restrict__ b2i,
               const float* __restrict__ b1c, const float* __restrict__ b2c,
               unsigned short* __restrict__ hbf)
{
    __shared__ __align__(16) unsigned short As[128][32];
    __shared__ __align__(16) unsigned short Ws[128][32];

    const int mt = blockIdx.x;
    const bool img = mt < MTI;
    const int row0 = img ? mt * 128 : 2048 + (mt - MTI) * 128;
    const unsigned short* W = img ? wpi : wpc;
    const float* b1 = img ? b1i : b1c;
    const float* b2 = img ? b2i : b2c;
    const int x = blockIdx.y;              // phys col tile 0..63
    const int bn = x * 128;

    const int t = threadIdx.x, lane = t & 63, wid = t >> 6;
    const int wm = wid >> 1, wn = wid & 1;
    const int srow = (wid << 5) + (lane >> 2);
    const int scol = (lane & 3) << 3;
    const unsigned short* Ag0 = n2 + (size_t)(row0 + srow)      * HDIM + scol;
    const unsigned short* Ag1 = n2 + (size_t)(row0 + srow + 16) * HDIM + scol;
    const unsigned short* Wg0 = W  + (size_t)(bn + srow)        * HDIM + scol;
    const unsigned short* Wg1 = W  + (size_t)(bn + srow + 16)   * HDIM + scol;
    unsigned short* lA0 = &As[(wid << 5)     ][0];
    unsigned short* lA1 = &As[(wid << 5) + 16][0];
    unsigned short* lW0 = &Ws[(wid << 5)     ][0];
    unsigned short* lW1 = &Ws[(wid << 5) + 16][0];

    const int fr = lane & 15, kg = lane >> 4, ko = kg << 3;
    f32x4 acc[4][4] = {};

    for (int k0 = 0; k0 < HDIM; k0 += 32) {
        __syncthreads();
        gload_lds16(Ag0 + k0, lA0);
        gload_lds16(Ag1 + k0, lA1);
        gload_lds16(Wg0 + k0, lW0);
        gload_lds16(Wg1 + k0, lW1);
        __syncthreads();
        bf16x8 aF[4], bF[4];
#pragma unroll
        for (int m = 0; m < 4; ++m) aF[m] = *(const bf16x8*)&As[wm*64 + m*16 + fr][ko];
#pragma unroll
        for (int n = 0; n < 4; ++n) bF[n] = *(const bf16x8*)&Ws[wn*64 + n*16 + fr][ko];
#pragma unroll
        for (int m = 0; m < 4; ++m)
#pragma unroll
            for (int n = 0; n < 4; ++n)
                acc[m][n] = __builtin_amdgcn_mfma_f32_16x16x32_bf16(aF[m], bF[n], acc[m][n], 0,0,0);
    }

    // epilogue: pairs (nt=0,1) and (nt=2,3): logical col lc = (4x+2wn+p)*16+fr
#pragma unroll
    for (int p = 0; p < 2; ++p) {
        const int lc = (4*x + 2*wn + p) * 16 + fr;        // 0..4095
        const float b1v = b1[lc], b2v = b2[lc];
#pragma unroll
        for (int m = 0; m < 4; ++m) {
#pragma unroll
            for (int j = 0; j < 4; ++j) {
                const int row = row0 + wm*64 + m*16 + (kg << 2) + j;
                float g1 = acc[m][2*p    ][j] + b1v;
                float g2 = acc[m][2*p + 1][j] + b2v;
                float hv = (g1 / (1.0f + __expf(-g1))) * g2;
                hbf[(size_t)row * MLPD + lc] = f2bf(hv);
            }
        }
    }
}

// ---------------------------------------------------------------------------
// Grouped N-narrow GEMM (BM=128,BN=64) with split-K; atomic f32 accumulate.
__global__ __launch_bounds__(256)
void nk_gemm(const unsigned short* __restrict__ A, int K,
             const unsigned short* __restrict__ Wimg, const unsigned short* __restrict__ Wcond,
             float* __restrict__ out, int kchunk,
             const float* __restrict__ sci, const float* __restrict__ scc)
{
    __shared__ __align__(16) unsigned short As[128][32];
    __shared__ __align__(16) unsigned short Ws[64][32];

    const int mt = blockIdx.x;
    const bool img = mt < MTI;
    const int row0 = img ? mt * 128 : 2048 + (mt - MTI) * 128;
    const unsigned short* W = img ? Wimg : Wcond;
    const float sc = img ? (sci ? sci[0] : 1.0f) : (scc ? scc[0] : 1.0f);
    const int bn = blockIdx.y * 64;
    const int kbase = blockIdx.z * kchunk;

    const int t = threadIdx.x, lane = t & 63, wid = t >> 6;
    const int srowA = (wid << 5) + (lane >> 2);
    const int srowW = (wid << 4) + (lane >> 2);
    const int scol  = (lane & 3) << 3;
    const unsigned short* Ag0 = A + (size_t)(row0 + srowA)      * K + kbase + scol;
    const unsigned short* Ag1 = A + (size_t)(row0 + srowA + 16) * K + kbase + scol;
    const unsigned short* Wg  = W + (size_t)(bn + srowW)        * K + kbase + scol;
    unsigned short* lA0 = &As[(wid << 5)     ][0];
    unsigned short* lA1 = &As[(wid << 5) + 16][0];
    unsigned short* lW  = &Ws[(wid << 4)     ][0];

    const int fr = lane & 15, kg = lane >> 4, ko = kg << 3;
    f32x4 acc[2][4] = {};

    for (int k0 = 0; k0 < kchunk; k0 += 32) {
        __syncthreads();
        gload_lds16(Ag0 + k0, lA0);
        gload_lds16(Ag1 + k0, lA1);
        gload_lds16(Wg  + k0, lW);
        __syncthreads();
        bf16x8 aF[2], bF[4];
#pragma unroll
        for (int m = 0; m < 2; ++m) aF[m] = *(const bf16x8*)&As[(wid<<5) + m*16 + fr][ko];
#pragma unroll
        for (int n = 0; n < 4; ++n) bF[n] = *(const bf16x8*)&Ws[n*16 + fr][ko];
#pragma unroll
        for (int m = 0; m < 2; ++m)
#pragma unroll
            for (int n = 0; n < 4; ++n)
                acc[m][n] = __builtin_amdgcn_mfma_f32_16x16x32_bf16(aF[m], bF[n], acc[m][n], 0,0,0);
    }

#pragma unroll
    for (int n = 0; n < 4; ++n) {
        const int col = bn + n*16 + fr;
#pragma unroll
        for (int m = 0; m < 2; ++m) {
#pragma unroll
            for (int j = 0; j < 4; ++j) {
                const int row = row0 + (wid << 5) + m*16 + (kg << 2) + j;
                unsafeAtomicAdd(&out[(size_t)row * HDIM + col], sc * acc[m][n][j]);
            }
        }
    }
}

// ---------------------------------------------------------------------------
// In-place per-head RMSNorm + RoPE on qh,kh (q gets 1/8 fold). 4 waves/block,
// one (b,h,s) per wave.
__launch_bounds__(256)
__global__ void qkv_prep(unsigned short* __restrict__ qh, unsigned short* __restrict__ kh,
                         const float* __restrict__ img_qn, const float* __restrict__ img_kn,
                         const float* __restrict__ cond_qn, const float* __restrict__ cond_kn,
                         const float* __restrict__ icos, const float* __restrict__ isin,
                         const float* __restrict__ ccos, const float* __restrict__ csin)
{
    const int L = blockIdx.x * 4 + (threadIdx.x >> 6);   // 0 .. BB*NH*SEQ-1
    const int d = threadIdx.x & 63;
    const int b = L / (NH * SEQ);
    const int rem = L - b * NH * SEQ;
    const int h = rem / SEQ;
    const int s = rem - h * SEQ;

    const float *qw, *kw, *cs, *sn;
    if (s < LC) { qw = cond_qn; kw = cond_kn;
                  cs = ccos + (size_t)s * HD; sn = csin + (size_t)s * HD; }
    else        { qw = img_qn; kw = img_kn;
                  cs = icos + (size_t)(s - LC) * HD; sn = isin + (size_t)(s - LC) * HD; }
    const size_t idx = (((size_t)(b*NH + h)) * SEQ + s) * HD + d;
    float qv = bf2f(qh[idx]);
    float kv = bf2f(kh[idx]);

    float sq = qv * qv;
    for (int o = 32; o > 0; o >>= 1) sq += __shfl_xor(sq, o);
    float qn = qv * rsqrtf(sq * (1.0f / HD) + EPS) * qw[d];
    float sk = kv * kv;
    for (int o = 32; o > 0; o >>= 1) sk += __shfl_xor(sk, o);
    float kn = kv * rsqrtf(sk * (1.0f / HD) + EPS) * kw[d];

    const float c = cs[d], s_ = sn[d];
    float qp = __shfl_xor(qn, 32);
    float kp = __shfl_xor(kn, 32);
    float qrot = (d < 32) ? -qp : qp;
    float krot = (d < 32) ? -kp : kp;
    qh[idx] = f2bf((qn * c + qrot * s_) * 0.125f);
    kh[idx] = f2bf(kn * c + krot * s_);
}

// ---------------------------------------------------------------------------
// MFMA flash attention v2: 256 thr (4 waves), q-tile 128 (32 q-rows/wave).
// Double-buffered K/VT staging (stage t+1 while computing t, one barrier/tile).
// S^T = mfma(K,Q) so each lane holds a full q-row slice -> softmax reduce is
// local chain + 2 shfl; P written as packed us4.
__global__ __launch_bounds__(256)
void attn_mfma(const unsigned short* __restrict__ qg,
               const unsigned short* __restrict__ kg,
               const unsigned short* __restrict__ vtg,
               unsigned short* __restrict__ o)
{
    const int q0  = blockIdx.x * 128;
    const int h   = blockIdx.y;
    const int b   = blockIdx.z;
    const int bh  = b * NH + h;
    const int t   = threadIdx.x;
    const int wid = t >> 6;
    const int lane = t & 63;
    const int g  = lane >> 4;
    const int fr = lane & 15;

    __shared__ __align__(16) unsigned short Ks [2][64 * 64];
    __shared__ __align__(16) unsigned short VTs[2][64 * 64];
    __shared__ __align__(16) unsigned short Ps [4][32][72];

    const unsigned short* qb  = qg  + (size_t)bh * SEQ * HD;
    const unsigned short* kb  = kg  + (size_t)bh * SEQ * HD;
    const unsigned short* vtb = vtg + (size_t)bh * HD * SEQ;

    // Q fragments: rows q0 + wid*32 + mt*16 + fr
    bf16x8 Qf[2][2];
#pragma unroll
    for (int mt = 0; mt < 2; ++mt)
#pragma unroll
        for (int kc = 0; kc < 2; ++kc)
            Qf[mt][kc] = *(const bf16x8*)&qb[(size_t)(q0 + wid*32 + mt*16 + fr) * HD
                                             + kc*32 + g*8];

    f32x4 O[2][4] = {};
    float mreg[2] = { -3e38f, -3e38f };   // running max for q-row fr (per mt)
    float lreg[2] = { 0.f, 0.f };

    // stage(tile, buf): 512 chunks each for K and VT, 2+2 per thread
#define STAGE(tile_, bufi_)                                                     \
    {                                                                           \
        _Pragma("unroll")                                                       \
        for (int i = 0; i < 2; ++i) {                                           \
            int chbase = i * 256 + wid * 64;                                    \
            int ch = chbase + lane;                                             \
            int r = ch >> 3, c = ch & 7;                                        \
            int cs_ = c ^ (r & 7);                                              \
            gload_lds16(kb  + (size_t)((tile_)*64 + r) * HD + cs_*8,            \
                        &Ks[bufi_][chbase * 8]);                                \
            gload_lds16(vtb + (size_t)r * SEQ + (tile_)*64 + cs_*8,             \
                        &VTs[bufi_][chbase * 8]);                               \
        }                                                                       \
    }

    STAGE(0, 0);
    __syncthreads();
    int buf = 0;

    for (int tile = 0; tile < SEQ / 64; ++tile) {
        if (tile + 1 < SEQ / 64) STAGE(tile + 1, buf ^ 1);

        // S^T = K Q^T : lane holds S[q=fr][kv=16nt+4g+j]
        f32x4 ST[2][4] = {};
#pragma unroll
        for (int kc = 0; kc < 2; ++kc)
#pragma unroll
            for (int nt = 0; nt < 4; ++nt) {
                int r = fr + 16*nt;
                bf16x8 kf = *(const bf16x8*)&Ks[buf][r*64 + (((g + 4*kc) ^ (r & 7)) * 8)];
#pragma unroll
                for (int mt = 0; mt < 2; ++mt)
                    ST[mt][nt] = __builtin_amdgcn_mfma_f32_16x16x32_bf16(
                        kf, Qf[mt][kc], ST[mt][nt], 0, 0, 0);
            }

        // online softmax, lane-local row
#pragma unroll
        for (int mt = 0; mt < 2; ++mt) {
            float tm = -3e38f;
#pragma unroll
            for (int nt = 0; nt < 4; ++nt)
#pragma unroll
                for (int j = 0; j < 4; ++j) tm = fmaxf(tm, ST[mt][nt][j]);
            tm = fmaxf(tm, __shfl_xor(tm, 16));
            tm = fmaxf(tm, __shfl_xor(tm, 32));
            float mn = fmaxf(mreg[mt], tm);
            float al = __expf(mreg[mt] - mn);
            mreg[mt] = mn;
            float ls = 0.f;
#pragma unroll
            for (int nt = 0; nt < 4; ++nt) {
#pragma unroll
                for (int j = 0; j < 4; ++j) {
                    float p = __expf(ST[mt][nt][j] - mn);
                    ST[mt][nt][j] = p;
                    ls += p;
                }
            }
            ls += __shfl_xor(ls, 16);
            ls += __shfl_xor(ls, 32);
            lreg[mt] = al * lreg[mt] + ls;
            // rescale O rows (q = 4g+rg): fetch al of that row
            f32x4 alr;
#pragma unroll
            for (int rg = 0; rg < 4; ++rg) alr[rg] = __shfl(al, 4*g + rg);
#pragma unroll
            for (int dt = 0; dt < 4; ++dt) O[mt][dt] *= alr;
            // write P packed: Ps[wid][mt*16+fr][16nt+4g .. +3]
#pragma unroll
            for (int nt = 0; nt < 4; ++nt) {
                us4 pk = { f2bf(ST[mt][nt][0]), f2bf(ST[mt][nt][1]),
                           f2bf(ST[mt][nt][2]), f2bf(ST[mt][nt][3]) };
                *(us4*)&Ps[wid][mt*16 + fr][16*nt + 4*g] = pk;
            }
        }

        // O += P @ V
#pragma unroll
        for (int kc = 0; kc < 2; ++kc) {
            bf16x8 Pf[2];
#pragma unroll
            for (int mt = 0; mt < 2; ++mt)
                Pf[mt] = *(const bf16x8*)&Ps[wid][mt*16 + fr][kc*32 + g*8];
#pragma unroll
            for (int dt = 0; dt < 4; ++dt) {
                int r = fr + 16*dt;
                bf16x8 vf = *(const bf16x8*)&VTs[buf][r*64 + (((g + 4*kc) ^ (r & 7)) * 8)];
#pragma unroll
                for (int mt = 0; mt < 2; ++mt)
                    O[mt][dt] = __builtin_amdgcn_mfma_f32_16x16x32_bf16(
                        Pf[mt], vf, O[mt][dt], 0, 0, 0);
            }
        }

        __syncthreads();   // drains next-tile vmcnt + all waves done with buf
        buf ^= 1;
    }

#pragma unroll
    for (int mt = 0; mt < 2; ++mt) {
        const float linv = 1.0f / lreg[mt];
        f32x4 lv;
#pragma unroll
        for (int rg = 0; rg < 4; ++rg) lv[rg] = __shfl(linv, 4*g + rg);
#pragma unroll
        for (int rg = 0; rg < 4; ++rg) {
            const int s_tok = q0 + wid*32 + mt*16 + 4*g + rg;
            const size_t row = (s_tok < LC) ? (size_t)(2048 + b*LC + s_tok)
                                            : (size_t)(b*LI + (s_tok - LC));
#pragma unroll
            for (int dt = 0; dt < 4; ++dt)
                o[row * HDIM + h*HD + 16*dt + fr] = f2bf(O[mt][dt][rg] * lv[rg]);
        }
    }
#undef STAGE
}

// ---------------------------------------------------------------------------
extern "C" void kernel_launch(void* const* d_in, const int* in_sizes, int n_in,
                              void* d_out, int out_size, void* d_ws, size_t ws_size,
                              hipStream_t stream)
{
    const float* image_tokens = (const float*)d_in[0];
    const float* cond_tokens  = (const float*)d_in[1];
    const float* icos  = (const float*)d_in[2];
    const float* isin  = (const float*)d_in[3];
    const float* ccos  = (const float*)d_in[4];
    const float* csin  = (const float*)d_in[5];
    const float* img_n1w  = (const float*)d_in[6];
    const float* cond_n1w = (const float*)d_in[7];
    const float* img_qkv_w  = (const float*)d_in[8];
    const float* img_qkv_b  = (const float*)d_in[9];
    const float* cond_qkv_w = (const float*)d_in[10];
    const float* cond_qkv_b = (const float*)d_in[11];
    const float* img_qn  = (const float*)d_in[12];
    const float* img_kn  = (const float*)d_in[13];
    const float* cond_qn = (const float*)d_in[14];
    const float* cond_kn = (const float*)d_in[15];
    const float* img_out_w  = (const float*)d_in[16];
    const float* img_out_b  = (const float*)d_in[17];
    const float* cond_out_w = (const float*)d_in[18];
    const float* cond_out_b = (const float*)d_in[19];
    const float* img_n2w  = (const float*)d_in[20];
    const float* cond_n2w = (const float*)d_in[21];
    const float* img_w1 = (const float*)d_in[22];
    const float* img_b1 = (const float*)d_in[23];
    const float* img_w2 = (const float*)d_in[24];
    const float* img_b2 = (const float*)d_in[25];
    const float* img_w3 = (const float*)d_in[26];
    const float* img_b3 = (const float*)d_in[27];
    const float* cond_w1 = (const float*)d_in[28];
    const float* cond_b1 = (const float*)d_in[29];
    const float* cond_w2 = (const float*)d_in[30];
    const float* cond_b2 = (const float*)d_in[31];
    const float* cond_w3 = (const float*)d_in[32];
    const float* cond_b3 = (const float*)d_in[33];
    const float* alpha = (const float*)d_in[34];
    const float* beta  = (const float*)d_in[35];

    float* out = (float*)d_out;   // rows: img 0..2047, cond 2048..2559

    // Arena (unsigned short units). Peak 93.3 MB (same as R4-proven).
    unsigned short* u = (unsigned short*)d_ws;
    unsigned short* wp_i  = u + 0;          // [8192][1024] pair img
    unsigned short* wp_c  = u + 8388608;
    unsigned short* w3b_i = u + 16777216;   // [1024][4096]
    unsigned short* w3b_c = u + 20971520;
    unsigned short* wqb_i = u + 25165824;   // [3072][1024]
    unsigned short* wqb_c = u + 28311552;
    unsigned short* wob_i = u + 31457280;   // [1024][1024]
    unsigned short* wob_c = u + 32505856;
    unsigned short* xn = u + 33554432;      // [2560][1024] (dead after qkv_gemm)
    unsigned short* vt = u + 36175872;      // [32][64][1280] (dead after attn)
    unsigned short* qh = u + 38797312;      // [32][1280][64] (dead after attn)
    unsigned short* kh = u + 41418752;      //   "
    unsigned short* o  = u + 44040192;      // [2560][1024] (dead after out-proj)
    float*          op = (float*)(u + 38797312);  // f32 [2560][1024] over qh+kh (dead)
    unsigned short* n2 = u + 36175872;      // over vt (dead after attn)
    unsigned short* hbf = u + 25165824;     // [2560][4096] over wq+wo+xn (dead)

    // 1. pack all weights
    pack_weights<<<dim3(512, 8), 256, 0, stream>>>(
        img_w1, img_w2, cond_w1, cond_w2, img_w3, cond_w3,
        img_qkv_w, cond_qkv_w, img_out_w, cond_out_w,
        wp_i, wp_c, w3b_i, w3b_c, wqb_i, wqb_c, wob_i, wob_c);

    // 2. norm1
    rmsnorm1<<<MROWS, 256, 0, stream>>>(image_tokens, cond_tokens, img_n1w, cond_n1w, xn);

    // 3. grouped qkv GEMM -> qh/kh + transposed vt
    qkv_gemm<<<dim3(MTT, 24), 256, 0, stream>>>(
        xn, wqb_i, wqb_c, img_qkv_b, cond_qkv_b, qh, kh, vt);

    // 4. in-place per-head norm+rope on q,k
    qkv_prep<<<BB * NH * SEQ / 4, 256, 0, stream>>>(
        qh, kh, img_qn, img_kn, cond_qn, cond_kn, icos, isin, ccos, csin);

    // 5. flash attention -> o
    attn_mfma<<<dim3(SEQ / 128, NH, BB), 256, 0, stream>>>(qh, kh, vt, o);

    // 6. out-proj: op = bias; += o @ Wo^T (split-K=2, atomic)
    op_init<<<MROWS, 256, 0, stream>>>(img_out_b, cond_out_b, op);
    nk_gemm<<<dim3(MTT, 16, 2), 256, 0, stream>>>(
        o, HDIM, wob_i, wob_c, op, HDIM / 2, nullptr, nullptr);

    // 7. norm2 fused with residual
    rmsnorm2<<<MROWS, 256, 0, stream>>>(
        image_tokens, cond_tokens, op, img_n2w, cond_n2w, alpha, n2);

    // 8. pair GEMM (up1+up2, swiglu) -> hbf
    pair_gemm<<<dim3(MTT, 64), 256, 0, stream>>>(
        n2, wp_i, wp_c, img_b1, img_b2, cond_b1, cond_b2, hbf);

    // 9. down-proj + residuals -> out
    down_init<<<MROWS, 256, 0, stream>>>(
        image_tokens, cond_tokens, op, img_b3, cond_b3, alpha, beta, out);
    nk_gemm<<<dim3(MTT, 16, 4), 256, 0, stream>>>(
        hbf, MLPD, w3b_i, w3b_c, out, MLPD / 4, beta, nullptr);
}

// Round 6
// 292.806 us; speedup vs baseline: 12.1563x; 1.0059x over previous
//
#include <hip/hip_runtime.h>
#include <hip/hip_bf16.h>

// Problem constants
#define BB   2
#define LI   1024
#define LC   256
#define SEQ  1280      // LC + LI
#define HDIM 1024
#define NH   16
#define HD   64
#define MLPD 4096
#define EPS  1e-6f
#define MROWS 2560     // 2048 img rows then 512 cond rows
#define MTI  16        // img M-tiles (BM=128)
#define MTT  20        // total M-tiles (16 img + 4 cond)

typedef __bf16 bf16x8 __attribute__((ext_vector_type(8)));
typedef float f32x4 __attribute__((ext_vector_type(4)));
typedef unsigned short us4 __attribute__((ext_vector_type(4)));
typedef unsigned short us8 __attribute__((ext_vector_type(8)));

static __device__ __forceinline__ unsigned short f2bf(float f) {
    unsigned int u = __builtin_bit_cast(unsigned int, f);
    u += 0x7fffu + ((u >> 16) & 1u);
    return (unsigned short)(u >> 16);
}
static __device__ __forceinline__ float bf2f(unsigned short h) {
    unsigned int u = ((unsigned int)h) << 16;
    return __builtin_bit_cast(float, u);
}

// async global->LDS, 16B per lane. LDS dst = wave-uniform base + lane*16.
static __device__ __forceinline__ void gload_lds16(const void* g, void* l) {
    __builtin_amdgcn_global_load_lds((__attribute__((address_space(1))) void*)(g),
                                     (__attribute__((address_space(3))) void*)(l),
                                     16, 0, 0);
}

// ---------------------------------------------------------------------------
// One-shot weight pack: 8 segments. seg 0/1 interleave w1/w2 (16-col groups)
// into pair layout [8192][1024]; others plain f32->bf16 cvt.
__global__ __launch_bounds__(256)
void pack_weights(const float* __restrict__ w1i, const float* __restrict__ w2i,
                  const float* __restrict__ w1c, const float* __restrict__ w2c,
                  const float* __restrict__ w3i, const float* __restrict__ w3c,
                  const float* __restrict__ wqi, const float* __restrict__ wqc,
                  const float* __restrict__ woi, const float* __restrict__ woc,
                  unsigned short* __restrict__ wpi, unsigned short* __restrict__ wpc,
                  unsigned short* __restrict__ w3bi, unsigned short* __restrict__ w3bc,
                  unsigned short* __restrict__ wqbi, unsigned short* __restrict__ wqbc,
                  unsigned short* __restrict__ wobi, unsigned short* __restrict__ wobc)
{
    const int seg = blockIdx.y;
    const float* s0 = nullptr; const float* s1 = nullptr;
    unsigned short* dst = nullptr; int n4 = 0; bool pair = false;
    switch (seg) {
        case 0: pair = true; s0 = w1i; s1 = w2i; dst = wpi;  n4 = 8388608 / 4; break;
        case 1: pair = true; s0 = w1c; s1 = w2c; dst = wpc;  n4 = 8388608 / 4; break;
        case 2: s0 = w3i; dst = w3bi; n4 = 4194304 / 4; break;
        case 3: s0 = w3c; dst = w3bc; n4 = 4194304 / 4; break;
        case 4: s0 = wqi; dst = wqbi; n4 = 3145728 / 4; break;
        case 5: s0 = wqc; dst = wqbc; n4 = 3145728 / 4; break;
        case 6: s0 = woi; dst = wobi; n4 = 1048576 / 4; break;
        case 7: s0 = woc; dst = wobc; n4 = 1048576 / 4; break;
    }
    for (int i = blockIdx.x * 256 + threadIdx.x; i < n4; i += gridDim.x * 256) {
        float4 v;
        if (pair) {
            int p  = i >> 8;          // phys row (256 float4 per 1024-row)
            int k4 = i & 255;
            int g = p >> 4, r = p & 15;
            const float* s = (g & 1) ? s1 : s0;
            v = *(const float4*)&s[((size_t)((g >> 1) * 16 + r)) * 1024 + k4 * 4];
        } else {
            v = ((const float4*)s0)[i];
        }
        us4 o = { f2bf(v.x), f2bf(v.y), f2bf(v.z), f2bf(v.w) };
        ((us4*)dst)[i] = o;
    }
}

// ---------------------------------------------------------------------------
// norm1: rows 0..2047 img, 2048..2559 cond -> xn bf16 [2560][1024]
__global__ __launch_bounds__(256)
void rmsnorm1(const float* __restrict__ img, const float* __restrict__ cond,
              const float* __restrict__ wi, const float* __restrict__ wc,
              unsigned short* __restrict__ xn)
{
    const int row = blockIdx.x;
    const int t   = threadIdx.x;
    const float* x = (row < 2048) ? img + (size_t)row * HDIM
                                  : cond + (size_t)(row - 2048) * HDIM;
    const float* w = (row < 2048) ? wi : wc;
    float4 v = ((const float4*)x)[t];
    float ss = v.x*v.x + v.y*v.y + v.z*v.z + v.w*v.w;
    for (int o = 32; o > 0; o >>= 1) ss += __shfl_xor(ss, o);
    __shared__ float red[4];
    if ((t & 63) == 0) red[t >> 6] = ss;
    __syncthreads();
    float inv = rsqrtf((red[0]+red[1]+red[2]+red[3]) * (1.0f / HDIM) + EPS);
    float4 wv = ((const float4*)w)[t];
    us4 pk = { f2bf(v.x*inv*wv.x), f2bf(v.y*inv*wv.y),
               f2bf(v.z*inv*wv.z), f2bf(v.w*inv*wv.w) };
    *(us4*)&xn[(size_t)row * HDIM + t * 4] = pk;
}

// norm2 fused residual: val = tok + sc*op ; rmsnorm -> n2 bf16
__global__ __launch_bounds__(256)
void rmsnorm2(const float* __restrict__ img_tok, const float* __restrict__ cond_tok,
              const float* __restrict__ op, const float* __restrict__ wi,
              const float* __restrict__ wc, const float* __restrict__ alpha,
              unsigned short* __restrict__ n2)
{
    const int row = blockIdx.x;
    const int t   = threadIdx.x;
    const bool img = row < 2048;
    const float sc = img ? alpha[0] : 1.0f;
    const float* tok = img ? img_tok + (size_t)row * HDIM
                           : cond_tok + (size_t)(row - 2048) * HDIM;
    const float* w = img ? wi : wc;
    float4 tv = ((const float4*)tok)[t];
    float4 ov = ((const float4*)(op + (size_t)row * HDIM))[t];
    float4 v = { tv.x + sc*ov.x, tv.y + sc*ov.y, tv.z + sc*ov.z, tv.w + sc*ov.w };
    float ss = v.x*v.x + v.y*v.y + v.z*v.z + v.w*v.w;
    for (int o = 32; o > 0; o >>= 1) ss += __shfl_xor(ss, o);
    __shared__ float red[4];
    if ((t & 63) == 0) red[t >> 6] = ss;
    __syncthreads();
    float inv = rsqrtf((red[0]+red[1]+red[2]+red[3]) * (1.0f / HDIM) + EPS);
    float4 wv = ((const float4*)w)[t];
    us4 pk = { f2bf(v.x*inv*wv.x), f2bf(v.y*inv*wv.y),
               f2bf(v.z*inv*wv.z), f2bf(v.w*inv*wv.w) };
    *(us4*)&n2[(size_t)row * HDIM + t * 4] = pk;
}

// op = bias (broadcast), per-stream bias
__global__ __launch_bounds__(256)
void op_init(const float* __restrict__ bi, const float* __restrict__ bc,
             float* __restrict__ op)
{
    const int row = blockIdx.x, t = threadIdx.x;
    const float* b = (row < 2048) ? bi : bc;
    ((float4*)(op + (size_t)row * HDIM))[t] = ((const float4*)b)[t];
}

// out = tok + sa*op + sm*b3   (split-K down-proj accumulates sm*acc on top)
__global__ __launch_bounds__(256)
void down_init(const float* __restrict__ img_tok, const float* __restrict__ cond_tok,
               const float* __restrict__ op, const float* __restrict__ b3i,
               const float* __restrict__ b3c, const float* __restrict__ alpha,
               const float* __restrict__ beta, float* __restrict__ out)
{
    const int row = blockIdx.x, t = threadIdx.x;
    const bool img = row < 2048;
    const float sa = img ? alpha[0] : 1.0f;
    const float sm = img ? beta[0]  : 1.0f;
    const float* tok = img ? img_tok + (size_t)row * HDIM
                           : cond_tok + (size_t)(row - 2048) * HDIM;
    const float* b3 = img ? b3i : b3c;
    float4 tv = ((const float4*)tok)[t];
    float4 ov = ((const float4*)(op + (size_t)row * HDIM))[t];
    float4 bv = ((const float4*)b3)[t];
    float4 o4 = { tv.x + sa*ov.x + sm*bv.x, tv.y + sa*ov.y + sm*bv.y,
                  tv.z + sa*ov.z + sm*bv.z, tv.w + sa*ov.w + sm*bv.w };
    ((float4*)(out + (size_t)row * HDIM))[t] = o4;
}

// ---------------------------------------------------------------------------
// Grouped QKV GEMM (BM=128,BN=128,K=1024): A=xn [2560][1024]; W per group.
// Scatter epilogue: q,k -> [b*NH+h][SEQ][64]; v -> TRANSPOSED vt [b*NH+h][d][SEQ].
__global__ __launch_bounds__(256)
void qkv_gemm(const unsigned short* __restrict__ xn,
              const unsigned short* __restrict__ wqi, const unsigned short* __restrict__ wqc,
              const float* __restrict__ bi, const float* __restrict__ bc,
              unsigned short* __restrict__ qh, unsigned short* __restrict__ kh,
              unsigned short* __restrict__ vt)
{
    __shared__ __align__(16) unsigned short As[128][32];
    __shared__ __align__(16) unsigned short Ws[128][32];

    const int mt = blockIdx.x;
    const bool img = mt < MTI;
    const int row0 = img ? mt * 128 : 2048 + (mt - MTI) * 128;      // global A row
    const int grow0 = img ? mt * 128 : (mt - MTI) * 128;            // group-local
    const unsigned short* W = img ? wqi : wqc;
    const float* bias = img ? bi : bc;
    const int bn = blockIdx.y * 128;

    const int t = threadIdx.x, lane = t & 63, wid = t >> 6;
    const int wm = wid >> 1, wn = wid & 1;
    const int srow = (wid << 5) + (lane >> 2);
    const int scol = (lane & 3) << 3;
    const unsigned short* Ag0 = xn + (size_t)(row0 + srow)      * HDIM + scol;
    const unsigned short* Ag1 = xn + (size_t)(row0 + srow + 16) * HDIM + scol;
    const unsigned short* Wg0 = W  + (size_t)(bn + srow)        * HDIM + scol;
    const unsigned short* Wg1 = W  + (size_t)(bn + srow + 16)   * HDIM + scol;
    unsigned short* lA0 = &As[(wid << 5)     ][0];
    unsigned short* lA1 = &As[(wid << 5) + 16][0];
    unsigned short* lW0 = &Ws[(wid << 5)     ][0];
    unsigned short* lW1 = &Ws[(wid << 5) + 16][0];

    const int fr = lane & 15, kg = lane >> 4, ko = kg << 3;
    f32x4 acc[4][4] = {};

    for (int k0 = 0; k0 < HDIM; k0 += 32) {
        __syncthreads();
        gload_lds16(Ag0 + k0, lA0);
        gload_lds16(Ag1 + k0, lA1);
        gload_lds16(Wg0 + k0, lW0);
        gload_lds16(Wg1 + k0, lW1);
        __syncthreads();
        bf16x8 aF[4], bF[4];
#pragma unroll
        for (int m = 0; m < 4; ++m) aF[m] = *(const bf16x8*)&As[wm*64 + m*16 + fr][ko];
#pragma unroll
        for (int n = 0; n < 4; ++n) bF[n] = *(const bf16x8*)&Ws[wn*64 + n*16 + fr][ko];
#pragma unroll
        for (int m = 0; m < 4; ++m)
#pragma unroll
            for (int n = 0; n < 4; ++n)
                acc[m][n] = __builtin_amdgcn_mfma_f32_16x16x32_bf16(aF[m], bF[n], acc[m][n], 0,0,0);
    }

#pragma unroll
    for (int n = 0; n < 4; ++n) {
        const int gc = bn + wn*64 + n*16 + fr;            // 0..3071
        const int which = gc >> 10;                       // 0 q / 1 k / 2 v
        const int h = (gc >> 6) & 15, d = gc & 63;
        const float bv = bias[gc];
#pragma unroll
        for (int m = 0; m < 4; ++m) {
            const int gl0 = grow0 + wm*64 + m*16 + (kg << 2);    // group row, j=0
            int b, s0;
            if (img) { b = gl0 >> 10; s0 = LC + (gl0 & 1023); }
            else     { b = gl0 >> 8;  s0 = gl0 & 255; }
            if (which == 2) {
                // transposed V store: 4 consecutive s -> us4 pack
                us4 pk = { f2bf(acc[m][n][0] + bv), f2bf(acc[m][n][1] + bv),
                           f2bf(acc[m][n][2] + bv), f2bf(acc[m][n][3] + bv) };
                *(us4*)&vt[(((size_t)(b*NH + h)) * HD + d) * SEQ + s0] = pk;
            } else {
                unsigned short* dst = (which == 0) ? qh : kh;
#pragma unroll
                for (int j = 0; j < 4; ++j)
                    dst[(((size_t)(b*NH + h)) * SEQ + s0 + j) * HD + d] = f2bf(acc[m][n][j] + bv);
            }
        }
    }
}

// ---------------------------------------------------------------------------
// Grouped pair GEMM (BM=128,BN=128 over N=8192 phys): swiglu epilogue -> hbf.
__global__ __launch_bounds__(256)
void pair_gemm(const unsigned short* __restrict__ n2,
               const unsigned short* __restrict__ wpi, const unsigned short* __restrict__ wpc,
               const float* __restrict__ b1i, const float* __restrict__ b2i,
               const float* __restrict__ b1c, const float* __restrict__ b2c,
               unsigned short* __restrict__ hbf)
{
    __shared__ __align__(16) unsigned short As[128][32];
    __shared__ __align__(16) unsigned short Ws[128][32];

    const int mt = blockIdx.x;
    const bool img = mt < MTI;
    const int row0 = img ? mt * 128 : 2048 + (mt - MTI) * 128;
    const unsigned short* W = img ? wpi : wpc;
    const float* b1 = img ? b1i : b1c;
    const float* b2 = img ? b2i : b2c;
    const int x = blockIdx.y;              // phys col tile 0..63
    const int bn = x * 128;

    const int t = threadIdx.x, lane = t & 63, wid = t >> 6;
    const int wm = wid >> 1, wn = wid & 1;
    const int srow = (wid << 5) + (lane >> 2);
    const int scol = (lane & 3) << 3;
    const unsigned short* Ag0 = n2 + (size_t)(row0 + srow)      * HDIM + scol;
    const unsigned short* Ag1 = n2 + (size_t)(row0 + srow + 16) * HDIM + scol;
    const unsigned short* Wg0 = W  + (size_t)(bn + srow)        * HDIM + scol;
    const unsigned short* Wg1 = W  + (size_t)(bn + srow + 16)   * HDIM + scol;
    unsigned short* lA0 = &As[(wid << 5)     ][0];
    unsigned short* lA1 = &As[(wid << 5) + 16][0];
    unsigned short* lW0 = &Ws[(wid << 5)     ][0];
    unsigned short* lW1 = &Ws[(wid << 5) + 16][0];

    const int fr = lane & 15, kg = lane >> 4, ko = kg << 3;
    f32x4 acc[4][4] = {};

    for (int k0 = 0; k0 < HDIM; k0 += 32) {
        __syncthreads();
        gload_lds16(Ag0 + k0, lA0);
        gload_lds16(Ag1 + k0, lA1);
        gload_lds16(Wg0 + k0, lW0);
        gload_lds16(Wg1 + k0, lW1);
        __syncthreads();
        bf16x8 aF[4], bF[4];
#pragma unroll
        for (int m = 0; m < 4; ++m) aF[m] = *(const bf16x8*)&As[wm*64 + m*16 + fr][ko];
#pragma unroll
        for (int n = 0; n < 4; ++n) bF[n] = *(const bf16x8*)&Ws[wn*64 + n*16 + fr][ko];
#pragma unroll
        for (int m = 0; m < 4; ++m)
#pragma unroll
            for (int n = 0; n < 4; ++n)
                acc[m][n] = __builtin_amdgcn_mfma_f32_16x16x32_bf16(aF[m], bF[n], acc[m][n], 0,0,0);
    }

    // epilogue: pairs (nt=0,1) and (nt=2,3): logical col lc = (4x+2wn+p)*16+fr
#pragma unroll
    for (int p = 0; p < 2; ++p) {
        const int lc = (4*x + 2*wn + p) * 16 + fr;        // 0..4095
        const float b1v = b1[lc], b2v = b2[lc];
#pragma unroll
        for (int m = 0; m < 4; ++m) {
#pragma unroll
            for (int j = 0; j < 4; ++j) {
                const int row = row0 + wm*64 + m*16 + (kg << 2) + j;
                float g1 = acc[m][2*p    ][j] + b1v;
                float g2 = acc[m][2*p + 1][j] + b2v;
                float hv = (g1 / (1.0f + __expf(-g1))) * g2;
                hbf[(size_t)row * MLPD + lc] = f2bf(hv);
            }
        }
    }
}

// ---------------------------------------------------------------------------
// Grouped split-K GEMM, 128x128 m97 structure, N=1024 fixed.
// blockIdx.x = bn tile (8, fastest -> L2-friendly), y = mt (20), z = k-chunk.
// Epilogue: out[row][col] += sc * acc  via f32 atomics.
__global__ __launch_bounds__(256)
void skg_gemm(const unsigned short* __restrict__ A, int K,
              const unsigned short* __restrict__ Wimg, const unsigned short* __restrict__ Wcond,
              float* __restrict__ out, int kchunk,
              const float* __restrict__ sci, const float* __restrict__ scc)
{
    __shared__ __align__(16) unsigned short As[128][32];
    __shared__ __align__(16) unsigned short Ws[128][32];

    const int mt = blockIdx.y;
    const bool img = mt < MTI;
    const int row0 = img ? mt * 128 : 2048 + (mt - MTI) * 128;
    const unsigned short* W = img ? Wimg : Wcond;
    const float sc = img ? (sci ? sci[0] : 1.0f) : (scc ? scc[0] : 1.0f);
    const int bn = blockIdx.x * 128;
    const int kbase = blockIdx.z * kchunk;

    const int t = threadIdx.x, lane = t & 63, wid = t >> 6;
    const int wm = wid >> 1, wn = wid & 1;
    const int srow = (wid << 5) + (lane >> 2);
    const int scol = (lane & 3) << 3;
    const unsigned short* Ag0 = A + (size_t)(row0 + srow)      * K + kbase + scol;
    const unsigned short* Ag1 = A + (size_t)(row0 + srow + 16) * K + kbase + scol;
    const unsigned short* Wg0 = W + (size_t)(bn + srow)        * K + kbase + scol;
    const unsigned short* Wg1 = W + (size_t)(bn + srow + 16)   * K + kbase + scol;
    unsigned short* lA0 = &As[(wid << 5)     ][0];
    unsigned short* lA1 = &As[(wid << 5) + 16][0];
    unsigned short* lW0 = &Ws[(wid << 5)     ][0];
    unsigned short* lW1 = &Ws[(wid << 5) + 16][0];

    const int fr = lane & 15, kg = lane >> 4, ko = kg << 3;
    f32x4 acc[4][4] = {};

    for (int k0 = 0; k0 < kchunk; k0 += 32) {
        __syncthreads();
        gload_lds16(Ag0 + k0, lA0);
        gload_lds16(Ag1 + k0, lA1);
        gload_lds16(Wg0 + k0, lW0);
        gload_lds16(Wg1 + k0, lW1);
        __syncthreads();
        bf16x8 aF[4], bF[4];
#pragma unroll
        for (int m = 0; m < 4; ++m) aF[m] = *(const bf16x8*)&As[wm*64 + m*16 + fr][ko];
#pragma unroll
        for (int n = 0; n < 4; ++n) bF[n] = *(const bf16x8*)&Ws[wn*64 + n*16 + fr][ko];
#pragma unroll
        for (int m = 0; m < 4; ++m)
#pragma unroll
            for (int n = 0; n < 4; ++n)
                acc[m][n] = __builtin_amdgcn_mfma_f32_16x16x32_bf16(aF[m], bF[n], acc[m][n], 0,0,0);
    }

#pragma unroll
    for (int n = 0; n < 4; ++n) {
        const int col = bn + wn*64 + n*16 + fr;
#pragma unroll
        for (int m = 0; m < 4; ++m) {
            const int r0 = row0 + wm*64 + m*16 + (kg << 2);
#pragma unroll
            for (int j = 0; j < 4; ++j)
                unsafeAtomicAdd(&out[(size_t)(r0 + j) * HDIM + col], sc * acc[m][n][j]);
        }
    }
}

// ---------------------------------------------------------------------------
// In-place per-head RMSNorm + RoPE on qh,kh (q gets 1/8 fold). 4 waves/block,
// one (b,h,s) per wave.
__launch_bounds__(256)
__global__ void qkv_prep(unsigned short* __restrict__ qh, unsigned short* __restrict__ kh,
                         const float* __restrict__ img_qn, const float* __restrict__ img_kn,
                         const float* __restrict__ cond_qn, const float* __restrict__ cond_kn,
                         const float* __restrict__ icos, const float* __restrict__ isin,
                         const float* __restrict__ ccos, const float* __restrict__ csin)
{
    const int L = blockIdx.x * 4 + (threadIdx.x >> 6);   // 0 .. BB*NH*SEQ-1
    const int d = threadIdx.x & 63;
    const int b = L / (NH * SEQ);
    const int rem = L - b * NH * SEQ;
    const int h = rem / SEQ;
    const int s = rem - h * SEQ;

    const float *qw, *kw, *cs, *sn;
    if (s < LC) { qw = cond_qn; kw = cond_kn;
                  cs = ccos + (size_t)s * HD; sn = csin + (size_t)s * HD; }
    else        { qw = img_qn; kw = img_kn;
                  cs = icos + (size_t)(s - LC) * HD; sn = isin + (size_t)(s - LC) * HD; }
    const size_t idx = (((size_t)(b*NH + h)) * SEQ + s) * HD + d;
    float qv = bf2f(qh[idx]);
    float kv = bf2f(kh[idx]);

    float sq = qv * qv;
    for (int o = 32; o > 0; o >>= 1) sq += __shfl_xor(sq, o);
    float qn = qv * rsqrtf(sq * (1.0f / HD) + EPS) * qw[d];
    float sk = kv * kv;
    for (int o = 32; o > 0; o >>= 1) sk += __shfl_xor(sk, o);
    float kn = kv * rsqrtf(sk * (1.0f / HD) + EPS) * kw[d];

    const float c = cs[d], s_ = sn[d];
    float qp = __shfl_xor(qn, 32);
    float kp = __shfl_xor(kn, 32);
    float qrot = (d < 32) ? -qp : qp;
    float krot = (d < 32) ? -kp : kp;
    qh[idx] = f2bf((qn * c + qrot * s_) * 0.125f);
    kh[idx] = f2bf(kn * c + krot * s_);
}

// ---------------------------------------------------------------------------
// MFMA flash attention v2: 256 thr (4 waves), q-tile 128 (32 q-rows/wave).
// Double-buffered K/VT staging; S^T = mfma(K,Q); packed us4 P writes.
__global__ __launch_bounds__(256)
void attn_mfma(const unsigned short* __restrict__ qg,
               const unsigned short* __restrict__ kg,
               const unsigned short* __restrict__ vtg,
               unsigned short* __restrict__ o)
{
    const int q0  = blockIdx.x * 128;
    const int h   = blockIdx.y;
    const int b   = blockIdx.z;
    const int bh  = b * NH + h;
    const int t   = threadIdx.x;
    const int wid = t >> 6;
    const int lane = t & 63;
    const int g  = lane >> 4;
    const int fr = lane & 15;

    __shared__ __align__(16) unsigned short Ks [2][64 * 64];
    __shared__ __align__(16) unsigned short VTs[2][64 * 64];
    __shared__ __align__(16) unsigned short Ps [4][32][72];

    const unsigned short* qb  = qg  + (size_t)bh * SEQ * HD;
    const unsigned short* kb  = kg  + (size_t)bh * SEQ * HD;
    const unsigned short* vtb = vtg + (size_t)bh * HD * SEQ;

    bf16x8 Qf[2][2];
#pragma unroll
    for (int mt = 0; mt < 2; ++mt)
#pragma unroll
        for (int kc = 0; kc < 2; ++kc)
            Qf[mt][kc] = *(const bf16x8*)&qb[(size_t)(q0 + wid*32 + mt*16 + fr) * HD
                                             + kc*32 + g*8];

    f32x4 O[2][4] = {};
    float mreg[2] = { -3e38f, -3e38f };
    float lreg[2] = { 0.f, 0.f };

#define STAGE(tile_, bufi_)                                                     \
    {                                                                           \
        _Pragma("unroll")                                                       \
        for (int i = 0; i < 2; ++i) {                                           \
            int chbase = i * 256 + wid * 64;                                    \
            int ch = chbase + lane;                                             \
            int r = ch >> 3, c = ch & 7;                                        \
            int cs_ = c ^ (r & 7);                                              \
            gload_lds16(kb  + (size_t)((tile_)*64 + r) * HD + cs_*8,            \
                        &Ks[bufi_][chbase * 8]);                                \
            gload_lds16(vtb + (size_t)r * SEQ + (tile_)*64 + cs_*8,             \
                        &VTs[bufi_][chbase * 8]);                               \
        }                                                                       \
    }

    STAGE(0, 0);
    __syncthreads();
    int buf = 0;

    for (int tile = 0; tile < SEQ / 64; ++tile) {
        if (tile + 1 < SEQ / 64) STAGE(tile + 1, buf ^ 1);

        f32x4 ST[2][4] = {};
#pragma unroll
        for (int kc = 0; kc < 2; ++kc)
#pragma unroll
            for (int nt = 0; nt < 4; ++nt) {
                int r = fr + 16*nt;
                bf16x8 kf = *(const bf16x8*)&Ks[buf][r*64 + (((g + 4*kc) ^ (r & 7)) * 8)];
#pragma unroll
                for (int mt = 0; mt < 2; ++mt)
                    ST[mt][nt] = __builtin_amdgcn_mfma_f32_16x16x32_bf16(
                        kf, Qf[mt][kc], ST[mt][nt], 0, 0, 0);
            }

#pragma unroll
        for (int mt = 0; mt < 2; ++mt) {
            float tm = -3e38f;
#pragma unroll
            for (int nt = 0; nt < 4; ++nt)
#pragma unroll
                for (int j = 0; j < 4; ++j) tm = fmaxf(tm, ST[mt][nt][j]);
            tm = fmaxf(tm, __shfl_xor(tm, 16));
            tm = fmaxf(tm, __shfl_xor(tm, 32));
            float mn = fmaxf(mreg[mt], tm);
            float al = __expf(mreg[mt] - mn);
            mreg[mt] = mn;
            float ls = 0.f;
#pragma unroll
            for (int nt = 0; nt < 4; ++nt) {
#pragma unroll
                for (int j = 0; j < 4; ++j) {
                    float p = __expf(ST[mt][nt][j] - mn);
                    ST[mt][nt][j] = p;
                    ls += p;
                }
            }
            ls += __shfl_xor(ls, 16);
            ls += __shfl_xor(ls, 32);
            lreg[mt] = al * lreg[mt] + ls;
            f32x4 alr;
#pragma unroll
            for (int rg = 0; rg < 4; ++rg) alr[rg] = __shfl(al, 4*g + rg);
#pragma unroll
            for (int dt = 0; dt < 4; ++dt) O[mt][dt] *= alr;
#pragma unroll
            for (int nt = 0; nt < 4; ++nt) {
                us4 pk = { f2bf(ST[mt][nt][0]), f2bf(ST[mt][nt][1]),
                           f2bf(ST[mt][nt][2]), f2bf(ST[mt][nt][3]) };
                *(us4*)&Ps[wid][mt*16 + fr][16*nt + 4*g] = pk;
            }
        }

#pragma unroll
        for (int kc = 0; kc < 2; ++kc) {
            bf16x8 Pf[2];
#pragma unroll
            for (int mt = 0; mt < 2; ++mt)
                Pf[mt] = *(const bf16x8*)&Ps[wid][mt*16 + fr][kc*32 + g*8];
#pragma unroll
            for (int dt = 0; dt < 4; ++dt) {
                int r = fr + 16*dt;
                bf16x8 vf = *(const bf16x8*)&VTs[buf][r*64 + (((g + 4*kc) ^ (r & 7)) * 8)];
#pragma unroll
                for (int mt = 0; mt < 2; ++mt)
                    O[mt][dt] = __builtin_amdgcn_mfma_f32_16x16x32_bf16(
                        Pf[mt], vf, O[mt][dt], 0, 0, 0);
            }
        }

        __syncthreads();
        buf ^= 1;
    }

#pragma unroll
    for (int mt = 0; mt < 2; ++mt) {
        const float linv = 1.0f / lreg[mt];
        f32x4 lv;
#pragma unroll
        for (int rg = 0; rg < 4; ++rg) lv[rg] = __shfl(linv, 4*g + rg);
#pragma unroll
        for (int rg = 0; rg < 4; ++rg) {
            const int s_tok = q0 + wid*32 + mt*16 + 4*g + rg;
            const size_t row = (s_tok < LC) ? (size_t)(2048 + b*LC + s_tok)
                                            : (size_t)(b*LI + (s_tok - LC));
#pragma unroll
            for (int dt = 0; dt < 4; ++dt)
                o[row * HDIM + h*HD + 16*dt + fr] = f2bf(O[mt][dt][rg] * lv[rg]);
        }
    }
#undef STAGE
}

// ---------------------------------------------------------------------------
extern "C" void kernel_launch(void* const* d_in, const int* in_sizes, int n_in,
                              void* d_out, int out_size, void* d_ws, size_t ws_size,
                              hipStream_t stream)
{
    const float* image_tokens = (const float*)d_in[0];
    const float* cond_tokens  = (const float*)d_in[1];
    const float* icos  = (const float*)d_in[2];
    const float* isin  = (const float*)d_in[3];
    const float* ccos  = (const float*)d_in[4];
    const float* csin  = (const float*)d_in[5];
    const float* img_n1w  = (const float*)d_in[6];
    const float* cond_n1w = (const float*)d_in[7];
    const float* img_qkv_w  = (const float*)d_in[8];
    const float* img_qkv_b  = (const float*)d_in[9];
    const float* cond_qkv_w = (const float*)d_in[10];
    const float* cond_qkv_b = (const float*)d_in[11];
    const float* img_qn  = (const float*)d_in[12];
    const float* img_kn  = (const float*)d_in[13];
    const float* cond_qn = (const float*)d_in[14];
    const float* cond_kn = (const float*)d_in[15];
    const float* img_out_w  = (const float*)d_in[16];
    const float* img_out_b  = (const float*)d_in[17];
    const float* cond_out_w = (const float*)d_in[18];
    const float* cond_out_b = (const float*)d_in[19];
    const float* img_n2w  = (const float*)d_in[20];
    const float* cond_n2w = (const float*)d_in[21];
    const float* img_w1 = (const float*)d_in[22];
    const float* img_b1 = (const float*)d_in[23];
    const float* img_w2 = (const float*)d_in[24];
    const float* img_b2 = (const float*)d_in[25];
    const float* img_w3 = (const float*)d_in[26];
    const float* img_b3 = (const float*)d_in[27];
    const float* cond_w1 = (const float*)d_in[28];
    const float* cond_b1 = (const float*)d_in[29];
    const float* cond_w2 = (const float*)d_in[30];
    const float* cond_b2 = (const float*)d_in[31];
    const float* cond_w3 = (const float*)d_in[32];
    const float* cond_b3 = (const float*)d_in[33];
    const float* alpha = (const float*)d_in[34];
    const float* beta  = (const float*)d_in[35];

    float* out = (float*)d_out;   // rows: img 0..2047, cond 2048..2559

    // Arena (unsigned short units). Peak 93.3 MB (same as R4/R5-proven).
    unsigned short* u = (unsigned short*)d_ws;
    unsigned short* wp_i  = u + 0;          // [8192][1024] pair img
    unsigned short* wp_c  = u + 8388608;
    unsigned short* w3b_i = u + 16777216;   // [1024][4096]
    unsigned short* w3b_c = u + 20971520;
    unsigned short* wqb_i = u + 25165824;   // [3072][1024]
    unsigned short* wqb_c = u + 28311552;
    unsigned short* wob_i = u + 31457280;   // [1024][1024]
    unsigned short* wob_c = u + 32505856;
    unsigned short* xn = u + 33554432;      // [2560][1024] (dead after qkv_gemm)
    unsigned short* vt = u + 36175872;      // [32][64][1280] (dead after attn)
    unsigned short* qh = u + 38797312;      // [32][1280][64] (dead after attn)
    unsigned short* kh = u + 41418752;      //   "
    unsigned short* o  = u + 44040192;      // [2560][1024] (dead after out-proj)
    float*          op = (float*)(u + 38797312);  // f32 [2560][1024] over qh+kh (dead)
    unsigned short* n2 = u + 36175872;      // over vt (dead after attn)
    unsigned short* hbf = u + 25165824;     // [2560][4096] over wq+wo+xn (dead)

    // 1. pack all weights
    pack_weights<<<dim3(512, 8), 256, 0, stream>>>(
        img_w1, img_w2, cond_w1, cond_w2, img_w3, cond_w3,
        img_qkv_w, cond_qkv_w, img_out_w, cond_out_w,
        wp_i, wp_c, w3b_i, w3b_c, wqb_i, wqb_c, wob_i, wob_c);

    // 2. norm1
    rmsnorm1<<<MROWS, 256, 0, stream>>>(image_tokens, cond_tokens, img_n1w, cond_n1w, xn);

    // 3. grouped qkv GEMM -> qh/kh + transposed vt
    qkv_gemm<<<dim3(MTT, 24), 256, 0, stream>>>(
        xn, wqb_i, wqb_c, img_qkv_b, cond_qkv_b, qh, kh, vt);

    // 4. in-place per-head norm+rope on q,k
    qkv_prep<<<BB * NH * SEQ / 4, 256, 0, stream>>>(
        qh, kh, img_qn, img_kn, cond_qn, cond_kn, icos, isin, ccos, csin);

    // 5. flash attention -> o
    attn_mfma<<<dim3(SEQ / 128, NH, BB), 256, 0, stream>>>(qh, kh, vt, o);

    // 6. out-proj: op = bias; += o @ Wo^T (128x128 split-K=2, atomic)
    op_init<<<MROWS, 256, 0, stream>>>(img_out_b, cond_out_b, op);
    skg_gemm<<<dim3(8, MTT, 2), 256, 0, stream>>>(
        o, HDIM, wob_i, wob_c, op, HDIM / 2, nullptr, nullptr);

    // 7. norm2 fused with residual
    rmsnorm2<<<MROWS, 256, 0, stream>>>(
        image_tokens, cond_tokens, op, img_n2w, cond_n2w, alpha, n2);

    // 8. pair GEMM (up1+up2, swiglu) -> hbf
    pair_gemm<<<dim3(MTT, 64), 256, 0, stream>>>(
        n2, wp_i, wp_c, img_b1, img_b2, cond_b1, cond_b2, hbf);

    // 9. down-proj + residuals -> out (128x128 split-K=4, atomic)
    down_init<<<MROWS, 256, 0, stream>>>(
        image_tokens, cond_tokens, op, img_b3, cond_b3, alpha, beta, out);
    skg_gemm<<<dim3(8, MTT, 4), 256, 0, stream>>>(
        hbf, MLPD, w3b_i, w3b_c, out, MLPD / 4, beta, nullptr);
}